// Round 7
// baseline (426.318 us; speedup 1.0000x reference)
//
#include <hip/hip_runtime.h>

#define NEG_SLOPE 0.2f
static constexpr int BLK = 256;

typedef short bf16x8 __attribute__((ext_vector_type(8)));
typedef float f32x4  __attribute__((ext_vector_type(4)));
typedef unsigned short u16x8 __attribute__((ext_vector_type(8)));
typedef unsigned short u16x4 __attribute__((ext_vector_type(4)));

static inline int cdiv(long a, long b){ return (int)((a + b - 1) / b); }

__device__ __forceinline__ unsigned short f2bf(float f){
    unsigned u = __float_as_uint(f);
    u += 0x7fff + ((u >> 16) & 1);          // round-to-nearest-even
    return (unsigned short)(u >> 16);
}
__device__ __forceinline__ float bf2f(unsigned short h){
    return __uint_as_float(((unsigned)h) << 16);
}

// ------------------- W prep: transpose + split into bf16 hi/lo -------------------
__global__ __launch_bounds__(BLK) void prep_w(
    const float* __restrict__ W, int CO,
    unsigned short* __restrict__ Wt_hi, unsigned short* __restrict__ Wt_lo)
{
    int i = blockIdx.x * BLK + threadIdx.x;
    if (i >= CO * 128) return;
    int c = i >> 7, k = i & 127;
    float w = W[k * CO + c];
    unsigned short hi = f2bf(w);
    Wt_hi[i] = hi;
    Wt_lo[i] = f2bf(w - bf2f(hi));
}

// ------------------- MFMA GEMM + attention dots (operand-swapped) -------------------
// D = W_frag x X_frag: lane holds H[r0+rl][c0+t*16+4g+{0..3}] -> packed coalesced stores.
// Each wave: 16 rows x CT*16 cols. CHUNKS = CO/(CT*16) waves per row-tile.
// as/ad accumulated via atomicAdd (zero-init required).
template<int CO, int CT, bool RELU_IN, bool BF16OUT>
__global__ __launch_bounds__(256, 4) void gemm_mfma(
    const float* __restrict__ X,
    const unsigned short* __restrict__ Wt_hi,
    const unsigned short* __restrict__ Wt_lo,
    const float* __restrict__ avs, const float* __restrict__ avd,
    void* __restrict__ Hout, float* __restrict__ as_out, float* __restrict__ ad_out,
    int N)
{
    constexpr int CHUNKS = CO / (CT * 16);
    int wave = threadIdx.x >> 6;
    int lane = threadIdx.x & 63;
    long wid = (long)blockIdx.x * 4 + wave;
    long nwav = (long)(N >> 4) * CHUNKS;
    if (wid >= nwav) return;
    int rt, ch;
    if (CHUNKS == 1){ rt = (int)wid; ch = 0; }
    else            { rt = (int)(wid >> 1); ch = (int)(wid & 1); }
    int r0 = rt << 4;
    int c0 = ch * (CT * 16);
    int rl = lane & 15, g = lane >> 4;

    const float* xrow = X + (long)(r0 + rl) * 128 + g * 8;
    const unsigned short* whp = Wt_hi + (long)(c0 + rl) * 128 + g * 8;
    const unsigned short* wlp = Wt_lo + (long)(c0 + rl) * 128 + g * 8;

    f32x4 acc[CT];
    #pragma unroll
    for (int t = 0; t < CT; t++) acc[t] = (f32x4)(0.f);

    // prologue: ks=0 W-hi + X
    bf16x8 wh[CT];
    #pragma unroll
    for (int t = 0; t < CT; t++) wh[t] = *(const bf16x8*)(whp + t * 2048);
    float4 xa = *(const float4*)(xrow);
    float4 xb = *(const float4*)(xrow + 4);

    #pragma unroll
    for (int ks = 0; ks < 4; ks++){
        // prefetch next ks (W-hi + X)
        bf16x8 nwh[CT]; float4 nxa, nxb;
        if (ks < 3){
            #pragma unroll
            for (int t = 0; t < CT; t++)
                nwh[t] = *(const bf16x8*)(whp + t * 2048 + (ks + 1) * 32);
            nxa = *(const float4*)(xrow + (ks + 1) * 32);
            nxb = *(const float4*)(xrow + (ks + 1) * 32 + 4);
        }
        // issue current W-lo early
        bf16x8 wl[CT];
        #pragma unroll
        for (int t = 0; t < CT; t++)
            wl[t] = *(const bf16x8*)(wlp + t * 2048 + ks * 32);

        // convert current X to split-bf16
        float xv[8] = {xa.x, xa.y, xa.z, xa.w, xb.x, xb.y, xb.z, xb.w};
        bf16x8 xhi, xlo;
        #pragma unroll
        for (int j = 0; j < 8; j++){
            float x = xv[j];
            if (RELU_IN) x = fmaxf(x, 0.f);
            unsigned short h = f2bf(x);
            xhi[j] = (short)h;
            xlo[j] = (short)f2bf(x - bf2f(h));
        }
        #pragma unroll
        for (int t = 0; t < CT; t++)
            acc[t] = __builtin_amdgcn_mfma_f32_16x16x32_bf16(wh[t], xhi, acc[t], 0, 0, 0);
        #pragma unroll
        for (int t = 0; t < CT; t++){
            acc[t] = __builtin_amdgcn_mfma_f32_16x16x32_bf16(wl[t], xhi, acc[t], 0, 0, 0);
            acc[t] = __builtin_amdgcn_mfma_f32_16x16x32_bf16(wh[t], xlo, acc[t], 0, 0, 0);
        }
        if (ks < 3){
            #pragma unroll
            for (int t = 0; t < CT; t++) wh[t] = nwh[t];
            xa = nxa; xb = nxb;
        }
    }

    // epilogue: packed coalesced H stores + as/ad partial dots
    float ps = 0.f, pd = 0.f;
    #pragma unroll
    for (int t = 0; t < CT; t++){
        int c = c0 + t * 16 + 4 * g;
        float4 vs4 = *(const float4*)(avs + c);
        float4 vd4 = *(const float4*)(avd + c);
        ps += acc[t][0]*vs4.x + acc[t][1]*vs4.y + acc[t][2]*vs4.z + acc[t][3]*vs4.w;
        pd += acc[t][0]*vd4.x + acc[t][1]*vd4.y + acc[t][2]*vd4.z + acc[t][3]*vd4.w;
        long base = (long)(r0 + rl) * CO + c;
        if (BF16OUT){
            u16x4 pk;
            #pragma unroll
            for (int r = 0; r < 4; r++) pk[r] = f2bf(acc[t][r]);
            *(u16x4*)((unsigned short*)Hout + base) = pk;
        } else {
            float4 pv;
            pv.x = acc[t][0]; pv.y = acc[t][1]; pv.z = acc[t][2]; pv.w = acc[t][3];
            *(float4*)((float*)Hout + base) = pv;
        }
    }
    ps += __shfl_xor(ps, 16, 64); ps += __shfl_xor(ps, 32, 64);
    pd += __shfl_xor(pd, 16, 64); pd += __shfl_xor(pd, 32, 64);
    if (g == 0){
        unsafeAtomicAdd(as_out + r0 + rl, ps);
        unsafeAtomicAdd(ad_out + r0 + rl, pd);
    }
}

// ------------------- CSR build via per-dst linked lists -------------------
__global__ __launch_bounds__(BLK) void link_k(
    const int* __restrict__ src, const int* __restrict__ dst, int E, int Etot,
    int* __restrict__ head, int2* __restrict__ pair)
{
    int e = blockIdx.x * BLK + threadIdx.x;
    if (e >= Etot) return;
    int s, d;
    if (e < E){ s = src[e]; d = dst[e]; } else { s = e - E; d = s; }
    int old = atomicExch(head + d, e);
    pair[e] = make_int2(old, s);        // (next, src) packed, 8B coalesced
}

__global__ __launch_bounds__(BLK) void deg_k(
    const int* __restrict__ head, const int2* __restrict__ pair,
    int* __restrict__ counts, int N)
{
    int n = blockIdx.x * BLK + threadIdx.x;
    if (n >= N) return;
    int c = head[n], len = 0;
    while (c >= 0){ len++; c = pair[c].x; }
    counts[n] = len;
}

__global__ __launch_bounds__(256) void scan1_k(
    const int* __restrict__ counts, int N, int* __restrict__ scan1, int* __restrict__ bsum)
{
    __shared__ int sh[256];
    int i = blockIdx.x * 256 + threadIdx.x;
    int v = (i < N) ? counts[i] : 0;
    sh[threadIdx.x] = v;
    __syncthreads();
    #pragma unroll
    for (int off = 1; off < 256; off <<= 1){
        int t = (threadIdx.x >= off) ? sh[threadIdx.x - off] : 0;
        __syncthreads();
        sh[threadIdx.x] += t;
        __syncthreads();
    }
    if (i < N) scan1[i] = sh[threadIdx.x];
    if (threadIdx.x == 255) bsum[blockIdx.x] = sh[255];
}

__global__ __launch_bounds__(256) void scan2_k(int* __restrict__ bsum, int nb)
{
    __shared__ int sh[256];
    int v = (threadIdx.x < nb) ? bsum[threadIdx.x] : 0;
    sh[threadIdx.x] = v;
    __syncthreads();
    #pragma unroll
    for (int off = 1; off < 256; off <<= 1){
        int t = (threadIdx.x >= off) ? sh[threadIdx.x - off] : 0;
        __syncthreads();
        sh[threadIdx.x] += t;
        __syncthreads();
    }
    if (threadIdx.x < nb) bsum[threadIdx.x] = sh[threadIdx.x] - v;  // exclusive
}

__global__ __launch_bounds__(256) void scan3_k(
    const int* __restrict__ counts, const int* __restrict__ scan1,
    const int* __restrict__ bsum, int N, int Etot, int* __restrict__ rowptr)
{
    int i = blockIdx.x * 256 + threadIdx.x;
    if (i < N) rowptr[i] = scan1[i] - counts[i] + bsum[blockIdx.x];
    if (i == 0) rowptr[N] = Etot;
}

__global__ __launch_bounds__(BLK) void unzip_k(
    const int* __restrict__ head, const int2* __restrict__ pair,
    const int* __restrict__ rowptr, int* __restrict__ csr_src, int N)
{
    int n = blockIdx.x * BLK + threadIdx.x;
    if (n >= N) return;
    int pos = rowptr[n];
    int c = head[n];
    while (c >= 0){
        int2 p = pair[c];
        csr_src[pos++] = p.y;
        c = p.x;
    }
}

// ------------------- fused softmax + aggregation, one wave per dst node ------------
template<int CO, bool BF16H>
__global__ __launch_bounds__(BLK) void node_agg(
    const int* __restrict__ rowptr, const int* __restrict__ csr_src,
    const float* __restrict__ as, const float* __restrict__ ad,
    const void* __restrict__ h, const float* __restrict__ bias,
    float* __restrict__ out, int N)
{
    constexpr int ELEMS = CO / 16;        // elems per lane in quarter-wave mode (8 or 4)
    int node = blockIdx.x * (BLK / 64) + (threadIdx.x >> 6);
    int lane = threadIdx.x & 63;
    if (node >= N) return;
    int start = rowptr[node];
    int deg   = rowptr[node + 1] - start;
    float adv = ad[node];
    int g  = lane >> 4;                   // quarter-group 0..3
    int ql = lane & 15;

    const unsigned short* hb = (const unsigned short*)h;
    const float*          hf = (const float*)h;

    if (deg <= 64){
        int   s = 0;
        float e = -1e30f;
        if (lane < deg){
            s = csr_src[start + lane];
            float v = as[s] + adv;
            e = v > 0.f ? v : NEG_SLOPE * v;
        }
        float m = e;
        #pragma unroll
        for (int off = 32; off; off >>= 1) m = fmaxf(m, __shfl_xor(m, off, 64));
        float ex = (lane < deg) ? __expf(e - m) : 0.f;
        float sum = ex;
        #pragma unroll
        for (int off = 32; off; off >>= 1) sum += __shfl_xor(sum, off, 64);
        float alpha = ex / (sum + 1e-16f);

        float acc[ELEMS];
        #pragma unroll
        for (int i = 0; i < ELEMS; i++) acc[i] = 0.f;

        int j = 0;
        for (; j + 7 < deg; j += 8){
            int e0 = j + g, e1 = j + 4 + g;
            int   s0 = __shfl(s, e0, 64),      s1 = __shfl(s, e1, 64);
            float a0 = __shfl(alpha, e0, 64),  a1 = __shfl(alpha, e1, 64);
            if (BF16H){
                u16x8 h0 = *(const u16x8*)(hb + (long)s0 * CO + ql * ELEMS);
                u16x8 h1 = *(const u16x8*)(hb + (long)s1 * CO + ql * ELEMS);
                #pragma unroll
                for (int i = 0; i < ELEMS; i++)
                    acc[i] += a0 * bf2f(h0[i]) + a1 * bf2f(h1[i]);
            } else {
                float4 h0 = *(const float4*)(hf + (long)s0 * CO + ql * ELEMS);
                float4 h1 = *(const float4*)(hf + (long)s1 * CO + ql * ELEMS);
                acc[0]       += a0 * h0.x + a1 * h1.x;
                acc[1]       += a0 * h0.y + a1 * h1.y;
                acc[2]       += a0 * h0.z + a1 * h1.z;
                acc[ELEMS-1] += a0 * h0.w + a1 * h1.w;
            }
        }
        for (; j + 3 < deg; j += 4){
            int e0 = j + g;
            int   s0 = __shfl(s, e0, 64);
            float a0 = __shfl(alpha, e0, 64);
            if (BF16H){
                u16x8 h0 = *(const u16x8*)(hb + (long)s0 * CO + ql * ELEMS);
                #pragma unroll
                for (int i = 0; i < ELEMS; i++) acc[i] += a0 * bf2f(h0[i]);
            } else {
                float4 h0 = *(const float4*)(hf + (long)s0 * CO + ql * ELEMS);
                acc[0] += a0 * h0.x; acc[1] += a0 * h0.y;
                acc[2] += a0 * h0.z; acc[ELEMS-1] += a0 * h0.w;
            }
        }
        if (j < deg){
            int rem = deg - j;
            int e0 = min(j + g, deg - 1);
            int   s0 = __shfl(s, e0, 64);
            float a0 = __shfl(alpha, e0, 64);
            if (g < rem){
                if (BF16H){
                    u16x8 h0 = *(const u16x8*)(hb + (long)s0 * CO + ql * ELEMS);
                    #pragma unroll
                    for (int i = 0; i < ELEMS; i++) acc[i] += a0 * bf2f(h0[i]);
                } else {
                    float4 h0 = *(const float4*)(hf + (long)s0 * CO + ql * ELEMS);
                    acc[0] += a0 * h0.x; acc[1] += a0 * h0.y;
                    acc[2] += a0 * h0.z; acc[ELEMS-1] += a0 * h0.w;
                }
            }
        }
        #pragma unroll
        for (int i = 0; i < ELEMS; i++){
            acc[i] += __shfl_xor(acc[i], 16, 64);
            acc[i] += __shfl_xor(acc[i], 32, 64);
        }
        if (g == 0){
            float* o = out + (long)node * CO + ql * ELEMS;
            #pragma unroll
            for (int i = 0; i < ELEMS; i += 4){
                float4 ov;
                ov.x = acc[i+0] + bias[ql * ELEMS + i + 0];
                ov.y = acc[i+1] + bias[ql * ELEMS + i + 1];
                ov.z = acc[i+2] + bias[ql * ELEMS + i + 2];
                ov.w = acc[i+3] + bias[ql * ELEMS + i + 3];
                *(float4*)(o + i) = ov;
            }
        }
    } else {
        constexpr int VPL = CO / 64;
        float accf[VPL];
        #pragma unroll
        for (int i = 0; i < VPL; i++) accf[i] = 0.f;
        float m = -1e30f;
        for (int jj = lane; jj < deg; jj += 64){
            int sj = csr_src[start + jj];
            float v = as[sj] + adv; v = v > 0.f ? v : NEG_SLOPE * v;
            m = fmaxf(m, v);
        }
        #pragma unroll
        for (int off = 32; off; off >>= 1) m = fmaxf(m, __shfl_xor(m, off, 64));
        float sum = 0.f;
        for (int jj = lane; jj < deg; jj += 64){
            int sj = csr_src[start + jj];
            float v = as[sj] + adv; v = v > 0.f ? v : NEG_SLOPE * v;
            sum += __expf(v - m);
        }
        #pragma unroll
        for (int off = 32; off; off >>= 1) sum += __shfl_xor(sum, off, 64);
        float inv = 1.f / (sum + 1e-16f);
        for (int jj = 0; jj < deg; jj++){
            int sj = csr_src[start + jj];
            float v = as[sj] + adv; v = v > 0.f ? v : NEG_SLOPE * v;
            float aj = __expf(v - m) * inv;
            if (BF16H){
                const unsigned short* hr = hb + (long)sj * CO + lane * VPL;
                #pragma unroll
                for (int i = 0; i < VPL; i++) accf[i] += aj * bf2f(hr[i]);
            } else {
                const float* hr = hf + (long)sj * CO + lane * VPL;
                #pragma unroll
                for (int i = 0; i < VPL; i++) accf[i] += aj * hr[i];
            }
        }
        float* o = out + (long)node * CO + lane * VPL;
        #pragma unroll
        for (int i = 0; i < VPL; i++) o[i] = accf[i] + bias[lane * VPL + i];
    }
}

extern "C" void kernel_launch(void* const* d_in, const int* in_sizes, int n_in,
                              void* d_out, int out_size, void* d_ws, size_t ws_size,
                              hipStream_t stream)
{
    const float* fea  = (const float*)d_in[0];  // [B,N,128]
    const int*   ei   = (const int*)  d_in[1];  // [B,2,E]
    const float* W1   = (const float*)d_in[2];  // [128,128]
    const float* av_s1= (const float*)d_in[3];
    const float* av_d1= (const float*)d_in[4];
    const float* b1   = (const float*)d_in[5];
    const float* W2   = (const float*)d_in[6];  // [128,64]
    const float* av_s2= (const float*)d_in[7];
    const float* av_d2= (const float*)d_in[8];
    const float* b2   = (const float*)d_in[9];
    float* out = (float*)d_out;

    const int B = 2;
    const int N = out_size / (B * 64);          // 50000
    const int E = in_sizes[1] / (2 * B);        // 800000
    const int Etot = E + N;

    // workspace layout (float units)
    float* ws = (float*)d_ws;
    size_t off = 0;
    unsigned short* h1b = (unsigned short*)(ws + off); off += (size_t)N * 64;  // bf16 [N][128]
    float* agg1 = ws + off; off += (size_t)N * 128;
    float* h2   = ws + off; off += (size_t)N * 64;
    float* as1  = ws + off; off += N;   // as1,ad1,as2,ad2 contiguous (one memset)
    float* ad1  = ws + off; off += N;
    float* as2  = ws + off; off += N;
    float* ad2  = ws + off; off += N;
    int* counts = (int*)(ws + off); off += N;
    int* head   = (int*)(ws + off); off += N;
    int* scan1b = (int*)(ws + off); off += N;
    int* bsum   = (int*)(ws + off); off += 256;
    int* rowptr = (int*)(ws + off); off += (N + 2);  // padded to even
    int* csrsrc = (int*)(ws + off); off += Etot;
    off += (off & 1);                                // 8B align for pair
    int2* pair  = (int2*)(ws + off); off += (size_t)2 * Etot;
    unsigned short* wt1h = (unsigned short*)(ws + off); off += 128*128/2;
    unsigned short* wt1l = (unsigned short*)(ws + off); off += 128*128/2;
    unsigned short* wt2h = (unsigned short*)(ws + off); off += 64*128/2;
    unsigned short* wt2l = (unsigned short*)(ws + off); off += 64*128/2;

    const int nb = cdiv(N, 256);

    prep_w<<<cdiv(128*128, BLK), BLK, 0, stream>>>(W1, 128, wt1h, wt1l);
    prep_w<<<cdiv(64*128,  BLK), BLK, 0, stream>>>(W2, 64,  wt2h, wt2l);

    for (int b = 0; b < B; b++){
        const int* srcp = ei + (size_t)b * 2 * E;
        const int* dstp = srcp + E;
        const float* xb = fea + (size_t)b * N * 128;
        float* outb = out + (size_t)b * N * 64;

        // ---- CSR build via linked lists (shared by both layers) ----
        hipMemsetAsync(head, 0xFF, (size_t)N * sizeof(int), stream);   // head = -1
        hipMemsetAsync(as1, 0, (size_t)4 * N * sizeof(float), stream); // as1,ad1,as2,ad2 = 0
        link_k<<<cdiv(Etot, BLK), BLK, 0, stream>>>(srcp, dstp, E, Etot, head, pair);
        deg_k<<<cdiv(N, BLK), BLK, 0, stream>>>(head, pair, counts, N);
        scan1_k<<<nb, 256, 0, stream>>>(counts, N, scan1b, bsum);
        scan2_k<<<1, 256, 0, stream>>>(bsum, nb);
        scan3_k<<<nb, 256, 0, stream>>>(counts, scan1b, bsum, N, Etot, rowptr);
        unzip_k<<<cdiv(N, BLK), BLK, 0, stream>>>(head, pair, rowptr, csrsrc, N);

        // ---- layer 1 (h1 in bf16): 16 rows x 64 cols per wave, 2 col-chunks ----
        gemm_mfma<128,4,false,true><<<cdiv((long)(N/16)*2, 4), 256, 0, stream>>>(
            xb, wt1h, wt1l, av_s1, av_d1, h1b, as1, ad1, N);
        node_agg<128,true><<<cdiv(N, BLK/64), BLK, 0, stream>>>(rowptr, csrsrc, as1, ad1, h1b, b1, agg1, N);

        // ---- layer 2 (h2 in f32): 16 rows x 32 cols per wave, 2 col-chunks ----
        gemm_mfma<64,2,true,false><<<cdiv((long)(N/16)*2, 4), 256, 0, stream>>>(
            agg1, wt2h, wt2l, av_s2, av_d2, h2, as2, ad2, N);
        node_agg<64,false><<<cdiv(N, BLK/64), BLK, 0, stream>>>(rowptr, csrsrc, as2, ad2, h2, b2, outb, N);
    }
}

// Round 8
// 350.594 us; speedup vs baseline: 1.2160x; 1.2160x over previous
//
#include <hip/hip_runtime.h>

#define NEG_SLOPE 0.2f
static constexpr int BLK = 256;

typedef short bf16x8 __attribute__((ext_vector_type(8)));
typedef float f32x4  __attribute__((ext_vector_type(4)));
typedef unsigned short u16x8 __attribute__((ext_vector_type(8)));
typedef unsigned short u16x4 __attribute__((ext_vector_type(4)));

static inline int cdiv(long a, long b){ return (int)((a + b - 1) / b); }

__device__ __forceinline__ unsigned short f2bf(float f){
    unsigned u = __float_as_uint(f);
    u += 0x7fff + ((u >> 16) & 1);          // RNE
    return (unsigned short)(u >> 16);
}
__device__ __forceinline__ float bf2f(unsigned short h){
    return __uint_as_float(((unsigned)h) << 16);
}

// ---------------- per-graph pointer bundle ----------------
struct GP {
    const int* src; const int* dst; const float* X;
    int* head; int2* pair; int* counts; int* scan1b; int* bsum; int* rowptr; int* csrsrc;
    unsigned short* h1b; float* agg1; float* h2;
    float *as1, *ad1, *as2, *ad2; float* outp;
};

// ---------------- device bodies ----------------
// operand-swapped split-bf16 MFMA GEMM; one wave = 16 rows x CT*16 cols; CHUNKS=CO/(CT*16)
template<int CO, int CT, bool RELU_IN, bool BF16OUT>
__device__ __forceinline__ void gemm_dev(
    int bid, const float* __restrict__ X,
    const unsigned short* __restrict__ Wt_hi, const unsigned short* __restrict__ Wt_lo,
    const float* __restrict__ avs, const float* __restrict__ avd,
    void* __restrict__ Hout, float* __restrict__ as_out, float* __restrict__ ad_out, int N)
{
    constexpr int CHUNKS = CO / (CT * 16);
    int wave = threadIdx.x >> 6;
    int lane = threadIdx.x & 63;
    long wid = (long)bid * 4 + wave;
    long nwav = (long)(N >> 4) * CHUNKS;
    if (wid >= nwav) return;
    int rt, ch;
    if (CHUNKS == 1){ rt = (int)wid; ch = 0; }
    else            { rt = (int)(wid >> 1); ch = (int)(wid & 1); }
    int r0 = rt << 4;
    int c0 = ch * (CT * 16);
    int rl = lane & 15, g = lane >> 4;

    const float* xrow = X + (long)(r0 + rl) * 128 + g * 8;
    const unsigned short* whp = Wt_hi + (long)(c0 + rl) * 128 + g * 8;
    const unsigned short* wlp = Wt_lo + (long)(c0 + rl) * 128 + g * 8;

    f32x4 acc[CT];
    #pragma unroll
    for (int t = 0; t < CT; t++) acc[t] = (f32x4)(0.f);

    bf16x8 wh[CT];
    #pragma unroll
    for (int t = 0; t < CT; t++) wh[t] = *(const bf16x8*)(whp + t * 2048);
    float4 xa = *(const float4*)(xrow);
    float4 xb = *(const float4*)(xrow + 4);

    #pragma unroll
    for (int ks = 0; ks < 4; ks++){
        bf16x8 nwh[CT]; float4 nxa, nxb;
        if (ks < 3){
            #pragma unroll
            for (int t = 0; t < CT; t++)
                nwh[t] = *(const bf16x8*)(whp + t * 2048 + (ks + 1) * 32);
            nxa = *(const float4*)(xrow + (ks + 1) * 32);
            nxb = *(const float4*)(xrow + (ks + 1) * 32 + 4);
        }
        bf16x8 wl[CT];
        #pragma unroll
        for (int t = 0; t < CT; t++)
            wl[t] = *(const bf16x8*)(wlp + t * 2048 + ks * 32);

        float xv[8] = {xa.x, xa.y, xa.z, xa.w, xb.x, xb.y, xb.z, xb.w};
        bf16x8 xhi, xlo;
        #pragma unroll
        for (int j = 0; j < 8; j++){
            float x = xv[j];
            if (RELU_IN) x = fmaxf(x, 0.f);
            unsigned short h = f2bf(x);
            xhi[j] = (short)h;
            xlo[j] = (short)f2bf(x - bf2f(h));
        }
        #pragma unroll
        for (int t = 0; t < CT; t++)
            acc[t] = __builtin_amdgcn_mfma_f32_16x16x32_bf16(wh[t], xhi, acc[t], 0, 0, 0);
        #pragma unroll
        for (int t = 0; t < CT; t++){
            acc[t] = __builtin_amdgcn_mfma_f32_16x16x32_bf16(wl[t], xhi, acc[t], 0, 0, 0);
            acc[t] = __builtin_amdgcn_mfma_f32_16x16x32_bf16(wh[t], xlo, acc[t], 0, 0, 0);
        }
        if (ks < 3){
            #pragma unroll
            for (int t = 0; t < CT; t++) wh[t] = nwh[t];
            xa = nxa; xb = nxb;
        }
    }

    float ps = 0.f, pd = 0.f;
    #pragma unroll
    for (int t = 0; t < CT; t++){
        int c = c0 + t * 16 + 4 * g;
        float4 vs4 = *(const float4*)(avs + c);
        float4 vd4 = *(const float4*)(avd + c);
        ps += acc[t][0]*vs4.x + acc[t][1]*vs4.y + acc[t][2]*vs4.z + acc[t][3]*vs4.w;
        pd += acc[t][0]*vd4.x + acc[t][1]*vd4.y + acc[t][2]*vd4.z + acc[t][3]*vd4.w;
        long base = (long)(r0 + rl) * CO + c;
        if (BF16OUT){
            u16x4 pk;
            #pragma unroll
            for (int r = 0; r < 4; r++) pk[r] = f2bf(acc[t][r]);
            *(u16x4*)((unsigned short*)Hout + base) = pk;
        } else {
            float4 pv;
            pv.x = acc[t][0]; pv.y = acc[t][1]; pv.z = acc[t][2]; pv.w = acc[t][3];
            *(float4*)((float*)Hout + base) = pv;
        }
    }
    ps += __shfl_xor(ps, 16, 64); ps += __shfl_xor(ps, 32, 64);
    pd += __shfl_xor(pd, 16, 64); pd += __shfl_xor(pd, 32, 64);
    if (g == 0){
        unsafeAtomicAdd(as_out + r0 + rl, ps);
        unsafeAtomicAdd(ad_out + r0 + rl, pd);
    }
}

__device__ __forceinline__ void link_dev(
    int bid, const int* __restrict__ src, const int* __restrict__ dst,
    int E, int Etot, int* __restrict__ head, int2* __restrict__ pair)
{
    int e = bid * BLK + threadIdx.x;
    if (e >= Etot) return;
    int s, d;
    if (e < E){ s = src[e]; d = dst[e]; } else { s = e - E; d = s; }
    int old = atomicExch(head + d, e);
    pair[e] = make_int2(old, s);
}

// fused softmax + aggregation, one wave per dst node (quarter-wave gather)
template<int CO, bool BF16H>
__device__ __forceinline__ void agg_dev(
    int bid, const int* __restrict__ rowptr, const int* __restrict__ csr_src,
    const float* __restrict__ as, const float* __restrict__ ad,
    const void* __restrict__ h, const float* __restrict__ bias,
    float* __restrict__ out, int N)
{
    constexpr int ELEMS = CO / 16;
    int node = bid * (BLK / 64) + (threadIdx.x >> 6);
    int lane = threadIdx.x & 63;
    if (node >= N) return;
    int start = rowptr[node];
    int deg   = rowptr[node + 1] - start;
    float adv = ad[node];
    int g  = lane >> 4;
    int ql = lane & 15;

    const unsigned short* hb = (const unsigned short*)h;
    const float*          hf = (const float*)h;

    if (deg <= 64){
        int   s = 0;
        float e = -1e30f;
        if (lane < deg){
            s = csr_src[start + lane];
            float v = as[s] + adv;
            e = v > 0.f ? v : NEG_SLOPE * v;
        }
        float m = e;
        #pragma unroll
        for (int off = 32; off; off >>= 1) m = fmaxf(m, __shfl_xor(m, off, 64));
        float ex = (lane < deg) ? __expf(e - m) : 0.f;
        float sum = ex;
        #pragma unroll
        for (int off = 32; off; off >>= 1) sum += __shfl_xor(sum, off, 64);
        float alpha = ex / (sum + 1e-16f);

        float acc[ELEMS];
        #pragma unroll
        for (int i = 0; i < ELEMS; i++) acc[i] = 0.f;

        int j = 0;
        for (; j + 7 < deg; j += 8){
            int e0 = j + g, e1 = j + 4 + g;
            int   s0 = __shfl(s, e0, 64),      s1 = __shfl(s, e1, 64);
            float a0 = __shfl(alpha, e0, 64),  a1 = __shfl(alpha, e1, 64);
            if (BF16H){
                u16x8 h0 = *(const u16x8*)(hb + (long)s0 * CO + ql * ELEMS);
                u16x8 h1 = *(const u16x8*)(hb + (long)s1 * CO + ql * ELEMS);
                #pragma unroll
                for (int i = 0; i < ELEMS; i++)
                    acc[i] += a0 * bf2f(h0[i]) + a1 * bf2f(h1[i]);
            } else {
                float4 h0 = *(const float4*)(hf + (long)s0 * CO + ql * ELEMS);
                float4 h1 = *(const float4*)(hf + (long)s1 * CO + ql * ELEMS);
                acc[0]       += a0 * h0.x + a1 * h1.x;
                acc[1]       += a0 * h0.y + a1 * h1.y;
                acc[2]       += a0 * h0.z + a1 * h1.z;
                acc[ELEMS-1] += a0 * h0.w + a1 * h1.w;
            }
        }
        for (; j + 3 < deg; j += 4){
            int e0 = j + g;
            int   s0 = __shfl(s, e0, 64);
            float a0 = __shfl(alpha, e0, 64);
            if (BF16H){
                u16x8 h0 = *(const u16x8*)(hb + (long)s0 * CO + ql * ELEMS);
                #pragma unroll
                for (int i = 0; i < ELEMS; i++) acc[i] += a0 * bf2f(h0[i]);
            } else {
                float4 h0 = *(const float4*)(hf + (long)s0 * CO + ql * ELEMS);
                acc[0] += a0 * h0.x; acc[1] += a0 * h0.y;
                acc[2] += a0 * h0.z; acc[ELEMS-1] += a0 * h0.w;
            }
        }
        if (j < deg){
            int rem = deg - j;
            int e0 = min(j + g, deg - 1);
            int   s0 = __shfl(s, e0, 64);
            float a0 = __shfl(alpha, e0, 64);
            if (g < rem){
                if (BF16H){
                    u16x8 h0 = *(const u16x8*)(hb + (long)s0 * CO + ql * ELEMS);
                    #pragma unroll
                    for (int i = 0; i < ELEMS; i++) acc[i] += a0 * bf2f(h0[i]);
                } else {
                    float4 h0 = *(const float4*)(hf + (long)s0 * CO + ql * ELEMS);
                    acc[0] += a0 * h0.x; acc[1] += a0 * h0.y;
                    acc[2] += a0 * h0.z; acc[ELEMS-1] += a0 * h0.w;
                }
            }
        }
        #pragma unroll
        for (int i = 0; i < ELEMS; i++){
            acc[i] += __shfl_xor(acc[i], 16, 64);
            acc[i] += __shfl_xor(acc[i], 32, 64);
        }
        if (g == 0){
            float* o = out + (long)node * CO + ql * ELEMS;
            #pragma unroll
            for (int i = 0; i < ELEMS; i += 4){
                float4 ov;
                ov.x = acc[i+0] + bias[ql * ELEMS + i + 0];
                ov.y = acc[i+1] + bias[ql * ELEMS + i + 1];
                ov.z = acc[i+2] + bias[ql * ELEMS + i + 2];
                ov.w = acc[i+3] + bias[ql * ELEMS + i + 3];
                *(float4*)(o + i) = ov;
            }
        }
    } else {
        constexpr int VPL = CO / 64;
        float accf[VPL];
        #pragma unroll
        for (int i = 0; i < VPL; i++) accf[i] = 0.f;
        float m = -1e30f;
        for (int jj = lane; jj < deg; jj += 64){
            int sj = csr_src[start + jj];
            float v = as[sj] + adv; v = v > 0.f ? v : NEG_SLOPE * v;
            m = fmaxf(m, v);
        }
        #pragma unroll
        for (int off = 32; off; off >>= 1) m = fmaxf(m, __shfl_xor(m, off, 64));
        float sum = 0.f;
        for (int jj = lane; jj < deg; jj += 64){
            int sj = csr_src[start + jj];
            float v = as[sj] + adv; v = v > 0.f ? v : NEG_SLOPE * v;
            sum += __expf(v - m);
        }
        #pragma unroll
        for (int off = 32; off; off >>= 1) sum += __shfl_xor(sum, off, 64);
        float inv = 1.f / (sum + 1e-16f);
        for (int jj = 0; jj < deg; jj++){
            int sj = csr_src[start + jj];
            float v = as[sj] + adv; v = v > 0.f ? v : NEG_SLOPE * v;
            float aj = __expf(v - m) * inv;
            if (BF16H){
                const unsigned short* hr = hb + (long)sj * CO + lane * VPL;
                #pragma unroll
                for (int i = 0; i < VPL; i++) accf[i] += aj * bf2f(hr[i]);
            } else {
                const float* hr = hf + (long)sj * CO + lane * VPL;
                #pragma unroll
                for (int i = 0; i < VPL; i++) accf[i] += aj * hr[i];
            }
        }
        float* o = out + (long)node * CO + lane * VPL;
        #pragma unroll
        for (int i = 0; i < VPL; i++) o[i] = accf[i] + bias[lane * VPL + i];
    }
}

// ---------------- fused kernels ----------------
__global__ __launch_bounds__(BLK) void init2_k(GP a, GP b, int ng, int N){
    int i = blockIdx.x * BLK + threadIdx.x;
    if (i >= N) return;
    a.head[i] = -1;
    a.as1[i] = 0.f; a.ad1[i] = 0.f; a.as2[i] = 0.f; a.ad2[i] = 0.f;
    if (ng > 1){
        b.head[i] = -1;
        b.as1[i] = 0.f; b.ad1[i] = 0.f; b.as2[i] = 0.f; b.ad2[i] = 0.f;
    }
}

__global__ __launch_bounds__(BLK) void prep2_k(
    const float* __restrict__ W1, const float* __restrict__ W2,
    unsigned short* __restrict__ w1h, unsigned short* __restrict__ w1l,
    unsigned short* __restrict__ w2h, unsigned short* __restrict__ w2l)
{
    int i = blockIdx.x * BLK + threadIdx.x;
    if (i < 128 * 128){
        int c = i >> 7, k = i & 127;
        float w = W1[k * 128 + c];
        unsigned short hi = f2bf(w);
        w1h[i] = hi; w1l[i] = f2bf(w - bf2f(hi));
    } else {
        int j = i - 128 * 128;
        if (j < 64 * 128){
            int c = j >> 7, k = j & 127;
            float w = W2[k * 64 + c];
            unsigned short hi = f2bf(w);
            w2h[j] = hi; w2l[j] = f2bf(w - bf2f(hi));
        }
    }
}

// mega1: layer-1 GEMMs (both graphs) + link (both graphs), Bresenham-interleaved roles
__global__ __launch_bounds__(256, 4) void mega1_k(
    GP a, GP b, const unsigned short* w1h, const unsigned short* w1l,
    const float* avs1, const float* avd1,
    int GB_a, int GB_b, int LB_a, int LB_b, int E, int Etot, int N)
{
    int GT = GB_a + GB_b;
    int total = GT + LB_a + LB_b;
    int bid = blockIdx.x;
    long lo  = (long)bid * GT / total;
    long hi2 = (long)(bid + 1) * GT / total;
    if (hi2 > lo){
        int gi = (int)lo;
        if (gi < GB_a) gemm_dev<128,4,false,true>(gi, a.X, w1h, w1l, avs1, avd1, a.h1b, a.as1, a.ad1, N);
        else           gemm_dev<128,4,false,true>(gi - GB_a, b.X, w1h, w1l, avs1, avd1, b.h1b, b.as1, b.ad1, N);
    } else {
        int l = bid - (int)lo;
        if (l < LB_a) link_dev(l, a.src, a.dst, E, Etot, a.head, a.pair);
        else { l -= LB_a; if (l < LB_b) link_dev(l, b.src, b.dst, E, Etot, b.head, b.pair); }
    }
}

__global__ __launch_bounds__(256, 4) void gemm2_k(
    GP a, GP b, const unsigned short* w2h, const unsigned short* w2l,
    const float* avs2, const float* avd2, int GB_a, int GB_b, int N)
{
    int bid = blockIdx.x;
    if (bid < GB_a) gemm_dev<64,2,true,false>(bid, a.agg1, w2h, w2l, avs2, avd2, a.h2, a.as2, a.ad2, N);
    else { bid -= GB_a; if (bid < GB_b) gemm_dev<64,2,true,false>(bid, b.agg1, w2h, w2l, avs2, avd2, b.h2, b.as2, b.ad2, N); }
}

__global__ __launch_bounds__(BLK) void deg2_k(GP a, GP b, int NB_a, int NB_b, int N){
    int bid = blockIdx.x; const GP* g; int lb;
    if (bid < NB_a){ g = &a; lb = bid; }
    else { lb = bid - NB_a; if (lb >= NB_b) return; g = &b; }
    int n = lb * BLK + threadIdx.x;
    if (n >= N) return;
    int c = g->head[n], len = 0;
    while (c >= 0){ len++; c = g->pair[c].x; }
    g->counts[n] = len;
}

__global__ __launch_bounds__(256) void scan1_2k(GP a, GP b, int nb_a, int nb_b, int N){
    int bid = blockIdx.x; const GP* g; int lb;
    if (bid < nb_a){ g = &a; lb = bid; }
    else { lb = bid - nb_a; if (lb >= nb_b) return; g = &b; }
    __shared__ int sh[256];
    int i = lb * 256 + threadIdx.x;
    int v = (i < N) ? g->counts[i] : 0;
    sh[threadIdx.x] = v;
    __syncthreads();
    #pragma unroll
    for (int off = 1; off < 256; off <<= 1){
        int t = (threadIdx.x >= off) ? sh[threadIdx.x - off] : 0;
        __syncthreads();
        sh[threadIdx.x] += t;
        __syncthreads();
    }
    if (i < N) g->scan1b[i] = sh[threadIdx.x];
    if (threadIdx.x == 255) g->bsum[lb] = sh[255];
}

__global__ __launch_bounds__(256) void scan2_2k(GP a, GP b, int nb){
    const GP* g = (blockIdx.x == 0) ? &a : &b;
    __shared__ int sh[256];
    int v = (threadIdx.x < nb) ? g->bsum[threadIdx.x] : 0;
    sh[threadIdx.x] = v;
    __syncthreads();
    #pragma unroll
    for (int off = 1; off < 256; off <<= 1){
        int t = (threadIdx.x >= off) ? sh[threadIdx.x - off] : 0;
        __syncthreads();
        sh[threadIdx.x] += t;
        __syncthreads();
    }
    if (threadIdx.x < nb) g->bsum[threadIdx.x] = sh[threadIdx.x] - v;
}

__global__ __launch_bounds__(256) void scan3_2k(GP a, GP b, int nb_a, int nb_b, int N, int Etot){
    int bid = blockIdx.x; const GP* g; int lb;
    if (bid < nb_a){ g = &a; lb = bid; }
    else { lb = bid - nb_a; if (lb >= nb_b) return; g = &b; }
    int i = lb * 256 + threadIdx.x;
    if (i < N) g->rowptr[i] = g->scan1b[i] - g->counts[i] + g->bsum[lb];
    if (i == 0) g->rowptr[N] = Etot;
}

__global__ __launch_bounds__(BLK) void unzip2_k(GP a, GP b, int NB_a, int NB_b, int N){
    int bid = blockIdx.x; const GP* g; int lb;
    if (bid < NB_a){ g = &a; lb = bid; }
    else { lb = bid - NB_a; if (lb >= NB_b) return; g = &b; }
    int n = lb * BLK + threadIdx.x;
    if (n >= N) return;
    int pos = g->rowptr[n];
    int c = g->head[n];
    while (c >= 0){
        int2 p = g->pair[c];
        g->csrsrc[pos++] = p.y;
        c = p.x;
    }
}

template<int CO, bool BF16H>
__global__ __launch_bounds__(BLK) void agg2_k(GP a, GP b, const float* bias, int AB_a, int AB_b, int N){
    int bid = blockIdx.x; const GP* g; int lb;
    if (bid < AB_a){ g = &a; lb = bid; }
    else { lb = bid - AB_a; if (lb >= AB_b) return; g = &b; }
    const float* as; const float* ad; const void* h; float* outp;
    if constexpr (CO == 128){ as = g->as1; ad = g->ad1; h = g->h1b; outp = g->agg1; }
    else                    { as = g->as2; ad = g->ad2; h = g->h2;  outp = g->outp; }
    agg_dev<CO, BF16H>(lb, g->rowptr, g->csrsrc, as, ad, h, bias, outp, N);
}

// ---------------- host ----------------
extern "C" void kernel_launch(void* const* d_in, const int* in_sizes, int n_in,
                              void* d_out, int out_size, void* d_ws, size_t ws_size,
                              hipStream_t stream)
{
    const float* fea  = (const float*)d_in[0];
    const int*   ei   = (const int*)  d_in[1];
    const float* W1   = (const float*)d_in[2];
    const float* av_s1= (const float*)d_in[3];
    const float* av_d1= (const float*)d_in[4];
    const float* b1   = (const float*)d_in[5];
    const float* W2   = (const float*)d_in[6];
    const float* av_s2= (const float*)d_in[7];
    const float* av_d2= (const float*)d_in[8];
    const float* b2   = (const float*)d_in[9];
    float* out = (float*)d_out;

    const int B = 2;
    const int N = out_size / (B * 64);          // 50000
    const int E = in_sizes[1] / (2 * B);        // 800000
    const int Etot = E + N;

    // per-graph float count (with slack) and fused/seq decision
    size_t pg = (size_t)N*64 + (size_t)N*128 + (size_t)N*64 + 4*(size_t)N
              + 3*(size_t)N + 256 + (size_t)(N + 2) + (size_t)Etot + 2*(size_t)Etot + 8;
    size_t wtf = 8192 + 8192 + 4096 + 4096;
    bool fused = (ws_size >= (2 * pg + wtf + 64) * sizeof(float));
    int NG = fused ? 2 : 1;

    float* ws = (float*)d_ws;
    size_t off = 0;
    unsigned short* w1h = (unsigned short*)(ws + off); off += 8192;
    unsigned short* w1l = (unsigned short*)(ws + off); off += 8192;
    unsigned short* w2h = (unsigned short*)(ws + off); off += 4096;
    unsigned short* w2l = (unsigned short*)(ws + off); off += 4096;

    GP g[2];
    for (int gi = 0; gi < NG; gi++){
        GP p;
        p.h1b   = (unsigned short*)(ws + off); off += (size_t)N * 64;
        p.agg1  = ws + off; off += (size_t)N * 128;
        p.h2    = ws + off; off += (size_t)N * 64;
        p.as1   = ws + off; off += N;
        p.ad1   = ws + off; off += N;
        p.as2   = ws + off; off += N;
        p.ad2   = ws + off; off += N;
        p.head  = (int*)(ws + off); off += N;
        p.counts= (int*)(ws + off); off += N;
        p.scan1b= (int*)(ws + off); off += N;
        p.bsum  = (int*)(ws + off); off += 256;
        p.rowptr= (int*)(ws + off); off += (size_t)(N + 2);
        p.csrsrc= (int*)(ws + off); off += Etot;
        off += (off & 1);
        p.pair  = (int2*)(ws + off); off += 2 * (size_t)Etot;
        g[gi] = p;
    }

    const int GB1 = cdiv((long)(N / 16) * 2, 4);   // layer-1 gemm blocks per graph
    const int GB2 = cdiv((long)(N / 16) * 2, 4);   // layer-2 gemm blocks per graph
    const int LB  = cdiv(Etot, BLK);
    const int NB  = cdiv(N, BLK);
    const int nb  = cdiv(N, 256);
    const int AB  = cdiv(N, BLK / 64);

    prep2_k<<<cdiv(128*128 + 64*128, BLK), BLK, 0, stream>>>(W1, W2, w1h, w1l, w2h, w2l);

    if (fused){
        // bind per-graph IO
        for (int bi = 0; bi < 2; bi++){
            g[bi].src = ei + (size_t)bi * 2 * E;
            g[bi].dst = g[bi].src + E;
            g[bi].X   = fea + (size_t)bi * N * 128;
            g[bi].outp= out + (size_t)bi * N * 64;
        }
        init2_k<<<cdiv(N, BLK), BLK, 0, stream>>>(g[0], g[1], 2, N);
        mega1_k<<<2*GB1 + 2*LB, 256, 0, stream>>>(g[0], g[1], w1h, w1l, av_s1, av_d1,
                                                  GB1, GB1, LB, LB, E, Etot, N);
        deg2_k  <<<2*NB, BLK, 0, stream>>>(g[0], g[1], NB, NB, N);
        scan1_2k<<<2*nb, 256, 0, stream>>>(g[0], g[1], nb, nb, N);
        scan2_2k<<<2, 256, 0, stream>>>(g[0], g[1], nb);
        scan3_2k<<<2*nb, 256, 0, stream>>>(g[0], g[1], nb, nb, N, Etot);
        unzip2_k<<<2*NB, BLK, 0, stream>>>(g[0], g[1], NB, NB, N);
        agg2_k<128,true> <<<2*AB, BLK, 0, stream>>>(g[0], g[1], b1, AB, AB, N);
        gemm2_k <<<2*GB2, 256, 0, stream>>>(g[0], g[1], w2h, w2l, av_s2, av_d2, GB2, GB2, N);
        agg2_k<64,false> <<<2*AB, BLK, 0, stream>>>(g[0], g[1], b2, AB, AB, N);
    } else {
        // sequential fallback: one buffer set, per-graph pipeline (link+gemm still fused)
        for (int bi = 0; bi < B; bi++){
            GP p = g[0];
            p.src = ei + (size_t)bi * 2 * E;
            p.dst = p.src + E;
            p.X   = fea + (size_t)bi * N * 128;
            p.outp= out + (size_t)bi * N * 64;
            init2_k<<<cdiv(N, BLK), BLK, 0, stream>>>(p, p, 1, N);
            mega1_k<<<GB1 + LB, 256, 0, stream>>>(p, p, w1h, w1l, av_s1, av_d1,
                                                  GB1, 0, LB, 0, E, Etot, N);
            deg2_k  <<<NB, BLK, 0, stream>>>(p, p, NB, 0, N);
            scan1_2k<<<nb, 256, 0, stream>>>(p, p, nb, 0, N);
            scan2_2k<<<1, 256, 0, stream>>>(p, p, nb);
            scan3_2k<<<nb, 256, 0, stream>>>(p, p, nb, 0, N, Etot);
            unzip2_k<<<NB, BLK, 0, stream>>>(p, p, NB, 0, N);
            agg2_k<128,true> <<<AB, BLK, 0, stream>>>(p, p, b1, AB, 0, N);
            gemm2_k <<<GB2, 256, 0, stream>>>(p, p, w2h, w2l, av_s2, av_d2, GB2, 0, N);
            agg2_k<64,false> <<<AB, BLK, 0, stream>>>(p, p, b2, AB, 0, N);
        }
    }
}

// Round 9
// 305.467 us; speedup vs baseline: 1.3956x; 1.1477x over previous
//
#include <hip/hip_runtime.h>

#define NEG_SLOPE 0.2f
static constexpr int BLK = 256;

typedef short bf16x8 __attribute__((ext_vector_type(8)));
typedef float f32x4  __attribute__((ext_vector_type(4)));
typedef unsigned short u16x8 __attribute__((ext_vector_type(8)));
typedef unsigned short u16x4 __attribute__((ext_vector_type(4)));

template<int NE> struct uvec_t;
template<> struct uvec_t<4>{ using T = u16x4; };
template<> struct uvec_t<8>{ using T = u16x8; };

static inline int cdiv(long a, long b){ return (int)((a + b - 1) / b); }

__device__ __forceinline__ unsigned short f2bf(float f){
    unsigned u = __float_as_uint(f);
    u += 0x7fff + ((u >> 16) & 1);          // RNE
    return (unsigned short)(u >> 16);
}
__device__ __forceinline__ float bf2f(unsigned short h){
    return __uint_as_float(((unsigned)h) << 16);
}

// ---------------- per-graph pointer bundle ----------------
struct GP {
    const int* src; const int* dst; const float* X;
    int* head; int2* pair; int* counts; int* scan1b; int* bsum; int* rowptr; int* csrsrc;
    unsigned short* h1b; float* agg1; unsigned short* h2b;
    float *as1, *ad1, *as2, *ad2; float* outp;
};

// ---------------- LDS-staged split-bf16 MFMA GEMM ----------------
// Block = 4 row-tiles (64 rows) x one col-chunk (CT*16 cols). W chunk staged to LDS
// once per block with XOR swizzle (byte ^= ((row&7)<<4)) to avoid stride-256B bank
// conflicts. Inner loop: 8 global X loads + ds_read_b128 W frags + 3*CT MFMAs per ks.
template<int CO, int CT, bool RELU_IN, bool BF16OUT>
__device__ __forceinline__ void gemm_dev(
    int bid, const float* __restrict__ X,
    const unsigned short* __restrict__ Wt_hi, const unsigned short* __restrict__ Wt_lo,
    const float* __restrict__ avs, const float* __restrict__ avd,
    void* __restrict__ Hout, float* __restrict__ as_out, float* __restrict__ ad_out,
    int N, unsigned short* smem)
{
    constexpr int CHUNKS = CO / (CT * 16);
    constexpr int HWB = CT * 4096;           // bytes of hi matrix in LDS
    int ch, rtb;
    if (CHUNKS == 1){ ch = 0; rtb = bid; } else { ch = bid & 1; rtb = bid >> 1; }
    int c0 = ch * (CT * 16);

    // cooperative stage: [hi | lo] chunk, each iteration uniform hi-or-lo
    {
        const char* srch = (const char*)(Wt_hi + (size_t)c0 * 128);
        const char* srcl = (const char*)(Wt_lo + (size_t)c0 * 128);
        #pragma unroll
        for (int it = 0; it < CT * 2; ++it){
            int o = (it * 256 + (int)threadIdx.x) * 16;
            const char* sp = (o < HWB) ? (srch + o) : (srcl + (o - HWB));
            u16x8 v = *(const u16x8*)sp;
            int so = o ^ (((o >> 8) & 7) << 4);
            *(u16x8*)((char*)smem + so) = v;
        }
    }
    __syncthreads();

    int wave = threadIdx.x >> 6;
    int lane = threadIdx.x & 63;
    int rt = rtb * 4 + wave;
    if (rt >= (N >> 4)) return;
    int r0 = rt << 4;
    int rl = lane & 15, g = lane >> 4;
    const float* xrow = X + (long)(r0 + rl) * 128 + g * 8;

    f32x4 acc[CT];
    #pragma unroll
    for (int t = 0; t < CT; t++) acc[t] = (f32x4)(0.f);

    int sw = (rl & 7) << 4;
    #pragma unroll
    for (int ks = 0; ks < 4; ks++){
        float4 xa = *(const float4*)(xrow + ks * 32);
        float4 xb = *(const float4*)(xrow + ks * 32 + 4);
        float xv[8] = {xa.x, xa.y, xa.z, xa.w, xb.x, xb.y, xb.z, xb.w};
        bf16x8 xhi, xlo;
        #pragma unroll
        for (int j = 0; j < 8; j++){
            float x = xv[j];
            if (RELU_IN) x = fmaxf(x, 0.f);
            unsigned short h = f2bf(x);
            xhi[j] = (short)h;
            xlo[j] = (short)f2bf(x - bf2f(h));
        }
        int rbase = rl * 256 + ks * 64 + g * 16;
        #pragma unroll
        for (int t = 0; t < CT; t++){
            bf16x8 wh = *(const bf16x8*)((char*)smem + ((t * 4096 + rbase) ^ sw));
            bf16x8 wl = *(const bf16x8*)((char*)smem + ((HWB + t * 4096 + rbase) ^ sw));
            acc[t] = __builtin_amdgcn_mfma_f32_16x16x32_bf16(wh, xhi, acc[t], 0, 0, 0);
            acc[t] = __builtin_amdgcn_mfma_f32_16x16x32_bf16(wl, xhi, acc[t], 0, 0, 0);
            acc[t] = __builtin_amdgcn_mfma_f32_16x16x32_bf16(wh, xlo, acc[t], 0, 0, 0);
        }
    }

    float ps = 0.f, pd = 0.f;
    #pragma unroll
    for (int t = 0; t < CT; t++){
        int c = c0 + t * 16 + 4 * g;
        float4 vs4 = *(const float4*)(avs + c);
        float4 vd4 = *(const float4*)(avd + c);
        ps += acc[t][0]*vs4.x + acc[t][1]*vs4.y + acc[t][2]*vs4.z + acc[t][3]*vs4.w;
        pd += acc[t][0]*vd4.x + acc[t][1]*vd4.y + acc[t][2]*vd4.z + acc[t][3]*vd4.w;
        long base = (long)(r0 + rl) * CO + c;
        if (BF16OUT){
            u16x4 pk;
            #pragma unroll
            for (int r = 0; r < 4; r++) pk[r] = f2bf(acc[t][r]);
            *(u16x4*)((unsigned short*)Hout + base) = pk;
        } else {
            float4 pv;
            pv.x = acc[t][0]; pv.y = acc[t][1]; pv.z = acc[t][2]; pv.w = acc[t][3];
            *(float4*)((float*)Hout + base) = pv;
        }
    }
    ps += __shfl_xor(ps, 16, 64); ps += __shfl_xor(ps, 32, 64);
    pd += __shfl_xor(pd, 16, 64); pd += __shfl_xor(pd, 32, 64);
    if (g == 0){
        unsafeAtomicAdd(as_out + r0 + rl, ps);
        unsafeAtomicAdd(ad_out + r0 + rl, pd);
    }
}

__device__ __forceinline__ void link_dev(
    int bid, const int* __restrict__ src, const int* __restrict__ dst,
    int E, int Etot, int* __restrict__ head, int2* __restrict__ pair)
{
    int e = bid * BLK + threadIdx.x;
    if (e >= Etot) return;
    int s, d;
    if (e < E){ s = src[e]; d = dst[e]; } else { s = e - E; d = s; }
    int old = atomicExch(head + d, e);
    pair[e] = make_int2(old, s);
}

// fused softmax + aggregation, one wave per dst node (quarter-wave gather)
template<int CO, bool BF16H>
__device__ __forceinline__ void agg_dev(
    int bid, const int* __restrict__ rowptr, const int* __restrict__ csr_src,
    const float* __restrict__ as, const float* __restrict__ ad,
    const void* __restrict__ h, const float* __restrict__ bias,
    float* __restrict__ out, int N)
{
    constexpr int ELEMS = CO / 16;
    using uvec = typename uvec_t<ELEMS>::T;
    int node = bid * (BLK / 64) + (threadIdx.x >> 6);
    int lane = threadIdx.x & 63;
    if (node >= N) return;
    int start = rowptr[node];
    int deg   = rowptr[node + 1] - start;
    float adv = ad[node];
    int g  = lane >> 4;
    int ql = lane & 15;

    const unsigned short* hb = (const unsigned short*)h;
    const float*          hf = (const float*)h;

    if (deg <= 64){
        int   s = 0;
        float e = -1e30f;
        if (lane < deg){
            s = csr_src[start + lane];
            float v = as[s] + adv;
            e = v > 0.f ? v : NEG_SLOPE * v;
        }
        float m = e;
        #pragma unroll
        for (int off = 32; off; off >>= 1) m = fmaxf(m, __shfl_xor(m, off, 64));
        float ex = (lane < deg) ? __expf(e - m) : 0.f;
        float sum = ex;
        #pragma unroll
        for (int off = 32; off; off >>= 1) sum += __shfl_xor(sum, off, 64);
        float alpha = ex / (sum + 1e-16f);

        float acc[ELEMS];
        #pragma unroll
        for (int i = 0; i < ELEMS; i++) acc[i] = 0.f;

        int j = 0;
        for (; j + 7 < deg; j += 8){
            int e0 = j + g, e1 = j + 4 + g;
            int   s0 = __shfl(s, e0, 64),      s1 = __shfl(s, e1, 64);
            float a0 = __shfl(alpha, e0, 64),  a1 = __shfl(alpha, e1, 64);
            if (BF16H){
                uvec h0 = *(const uvec*)(hb + (long)s0 * CO + ql * ELEMS);
                uvec h1 = *(const uvec*)(hb + (long)s1 * CO + ql * ELEMS);
                #pragma unroll
                for (int i = 0; i < ELEMS; i++)
                    acc[i] += a0 * bf2f(h0[i]) + a1 * bf2f(h1[i]);
            } else {
                float4 h0 = *(const float4*)(hf + (long)s0 * CO + ql * ELEMS);
                float4 h1 = *(const float4*)(hf + (long)s1 * CO + ql * ELEMS);
                acc[0]       += a0 * h0.x + a1 * h1.x;
                acc[1]       += a0 * h0.y + a1 * h1.y;
                acc[2]       += a0 * h0.z + a1 * h1.z;
                acc[ELEMS-1] += a0 * h0.w + a1 * h1.w;
            }
        }
        for (; j + 3 < deg; j += 4){
            int e0 = j + g;
            int   s0 = __shfl(s, e0, 64);
            float a0 = __shfl(alpha, e0, 64);
            if (BF16H){
                uvec h0 = *(const uvec*)(hb + (long)s0 * CO + ql * ELEMS);
                #pragma unroll
                for (int i = 0; i < ELEMS; i++) acc[i] += a0 * bf2f(h0[i]);
            } else {
                float4 h0 = *(const float4*)(hf + (long)s0 * CO + ql * ELEMS);
                acc[0] += a0 * h0.x; acc[1] += a0 * h0.y;
                acc[2] += a0 * h0.z; acc[ELEMS-1] += a0 * h0.w;
            }
        }
        if (j < deg){
            int rem = deg - j;
            int e0 = min(j + g, deg - 1);
            int   s0 = __shfl(s, e0, 64);
            float a0 = __shfl(alpha, e0, 64);
            if (g < rem){
                if (BF16H){
                    uvec h0 = *(const uvec*)(hb + (long)s0 * CO + ql * ELEMS);
                    #pragma unroll
                    for (int i = 0; i < ELEMS; i++) acc[i] += a0 * bf2f(h0[i]);
                } else {
                    float4 h0 = *(const float4*)(hf + (long)s0 * CO + ql * ELEMS);
                    acc[0] += a0 * h0.x; acc[1] += a0 * h0.y;
                    acc[2] += a0 * h0.z; acc[ELEMS-1] += a0 * h0.w;
                }
            }
        }
        #pragma unroll
        for (int i = 0; i < ELEMS; i++){
            acc[i] += __shfl_xor(acc[i], 16, 64);
            acc[i] += __shfl_xor(acc[i], 32, 64);
        }
        if (g == 0){
            float* o = out + (long)node * CO + ql * ELEMS;
            #pragma unroll
            for (int i = 0; i < ELEMS; i += 4){
                float4 ov;
                ov.x = acc[i+0] + bias[ql * ELEMS + i + 0];
                ov.y = acc[i+1] + bias[ql * ELEMS + i + 1];
                ov.z = acc[i+2] + bias[ql * ELEMS + i + 2];
                ov.w = acc[i+3] + bias[ql * ELEMS + i + 3];
                *(float4*)(o + i) = ov;
            }
        }
    } else {
        constexpr int VPL = CO / 64;
        float accf[VPL];
        #pragma unroll
        for (int i = 0; i < VPL; i++) accf[i] = 0.f;
        float m = -1e30f;
        for (int jj = lane; jj < deg; jj += 64){
            int sj = csr_src[start + jj];
            float v = as[sj] + adv; v = v > 0.f ? v : NEG_SLOPE * v;
            m = fmaxf(m, v);
        }
        #pragma unroll
        for (int off = 32; off; off >>= 1) m = fmaxf(m, __shfl_xor(m, off, 64));
        float sum = 0.f;
        for (int jj = lane; jj < deg; jj += 64){
            int sj = csr_src[start + jj];
            float v = as[sj] + adv; v = v > 0.f ? v : NEG_SLOPE * v;
            sum += __expf(v - m);
        }
        #pragma unroll
        for (int off = 32; off; off >>= 1) sum += __shfl_xor(sum, off, 64);
        float inv = 1.f / (sum + 1e-16f);
        for (int jj = 0; jj < deg; jj++){
            int sj = csr_src[start + jj];
            float v = as[sj] + adv; v = v > 0.f ? v : NEG_SLOPE * v;
            float aj = __expf(v - m) * inv;
            if (BF16H){
                const unsigned short* hr = hb + (long)sj * CO + lane * VPL;
                #pragma unroll
                for (int i = 0; i < VPL; i++) accf[i] += aj * bf2f(hr[i]);
            } else {
                const float* hr = hf + (long)sj * CO + lane * VPL;
                #pragma unroll
                for (int i = 0; i < VPL; i++) accf[i] += aj * hr[i];
            }
        }
        float* o = out + (long)node * CO + lane * VPL;
        #pragma unroll
        for (int i = 0; i < VPL; i++) o[i] = accf[i] + bias[lane * VPL + i];
    }
}

// ---------------- fused kernels ----------------
__global__ __launch_bounds__(BLK) void init2_k(GP a, GP b, int ng, int N){
    int i = blockIdx.x * BLK + threadIdx.x;
    if (i >= N) return;
    a.head[i] = -1;
    a.as1[i] = 0.f; a.ad1[i] = 0.f; a.as2[i] = 0.f; a.ad2[i] = 0.f;
    if (ng > 1){
        b.head[i] = -1;
        b.as1[i] = 0.f; b.ad1[i] = 0.f; b.as2[i] = 0.f; b.ad2[i] = 0.f;
    }
}

__global__ __launch_bounds__(BLK) void prep2_k(
    const float* __restrict__ W1, const float* __restrict__ W2,
    unsigned short* __restrict__ w1h, unsigned short* __restrict__ w1l,
    unsigned short* __restrict__ w2h, unsigned short* __restrict__ w2l)
{
    int i = blockIdx.x * BLK + threadIdx.x;
    if (i < 128 * 128){
        int c = i >> 7, k = i & 127;
        float w = W1[k * 128 + c];
        unsigned short hi = f2bf(w);
        w1h[i] = hi; w1l[i] = f2bf(w - bf2f(hi));
    } else {
        int j = i - 128 * 128;
        if (j < 64 * 128){
            int c = j >> 7, k = j & 127;
            float w = W2[k * 64 + c];
            unsigned short hi = f2bf(w);
            w2h[j] = hi; w2l[j] = f2bf(w - bf2f(hi));
        }
    }
}

// mega1: layer-1 GEMMs (both graphs) + link (both graphs), Bresenham-interleaved
__global__ __launch_bounds__(256, 4) void mega1_k(
    GP a, GP b, const unsigned short* w1h, const unsigned short* w1l,
    const float* avs1, const float* avd1,
    int GB_a, int GB_b, int LB_a, int LB_b, int E, int Etot, int N)
{
    __shared__ unsigned short smem[16384];   // 32KB: W1 chunk hi+lo
    int GT = GB_a + GB_b;
    int total = GT + LB_a + LB_b;
    int bid = blockIdx.x;
    long lo  = (long)bid * GT / total;
    long hi2 = (long)(bid + 1) * GT / total;
    if (hi2 > lo){
        int gi = (int)lo;
        if (gi < GB_a) gemm_dev<128,4,false,true>(gi, a.X, w1h, w1l, avs1, avd1, a.h1b, a.as1, a.ad1, N, smem);
        else           gemm_dev<128,4,false,true>(gi - GB_a, b.X, w1h, w1l, avs1, avd1, b.h1b, b.as1, b.ad1, N, smem);
    } else {
        int l = bid - (int)lo;
        if (l < LB_a) link_dev(l, a.src, a.dst, E, Etot, a.head, a.pair);
        else { l -= LB_a; if (l < LB_b) link_dev(l, b.src, b.dst, E, Etot, b.head, b.pair); }
    }
}

__global__ __launch_bounds__(256, 4) void gemm2_k(
    GP a, GP b, const unsigned short* w2h, const unsigned short* w2l,
    const float* avs2, const float* avd2, int GB_a, int GB_b, int N)
{
    __shared__ unsigned short smem[8192];    // 16KB: W2 chunk hi+lo
    int bid = blockIdx.x;
    if (bid < GB_a) gemm_dev<64,2,true,true>(bid, a.agg1, w2h, w2l, avs2, avd2, a.h2b, a.as2, a.ad2, N, smem);
    else { bid -= GB_a; if (bid < GB_b) gemm_dev<64,2,true,true>(bid, b.agg1, w2h, w2l, avs2, avd2, b.h2b, b.as2, b.ad2, N, smem); }
}

__global__ __launch_bounds__(BLK) void deg2_k(GP a, GP b, int NB_a, int NB_b, int N){
    int bid = blockIdx.x; const GP* g; int lb;
    if (bid < NB_a){ g = &a; lb = bid; }
    else { lb = bid - NB_a; if (lb >= NB_b) return; g = &b; }
    int n = lb * BLK + threadIdx.x;
    if (n >= N) return;
    int c = g->head[n], len = 0;
    while (c >= 0){ len++; c = g->pair[c].x; }
    g->counts[n] = len;
}

__global__ __launch_bounds__(256) void scan1_2k(GP a, GP b, int nb_a, int nb_b, int N){
    int bid = blockIdx.x; const GP* g; int lb;
    if (bid < nb_a){ g = &a; lb = bid; }
    else { lb = bid - nb_a; if (lb >= nb_b) return; g = &b; }
    __shared__ int sh[256];
    int i = lb * 256 + threadIdx.x;
    int v = (i < N) ? g->counts[i] : 0;
    sh[threadIdx.x] = v;
    __syncthreads();
    #pragma unroll
    for (int off = 1; off < 256; off <<= 1){
        int t = (threadIdx.x >= off) ? sh[threadIdx.x - off] : 0;
        __syncthreads();
        sh[threadIdx.x] += t;
        __syncthreads();
    }
    if (i < N) g->scan1b[i] = sh[threadIdx.x];
    if (threadIdx.x == 255) g->bsum[lb] = sh[255];
}

__global__ __launch_bounds__(256) void scan2_2k(GP a, GP b, int nb){
    const GP* g = (blockIdx.x == 0) ? &a : &b;
    __shared__ int sh[256];
    int v = (threadIdx.x < nb) ? g->bsum[threadIdx.x] : 0;
    sh[threadIdx.x] = v;
    __syncthreads();
    #pragma unroll
    for (int off = 1; off < 256; off <<= 1){
        int t = (threadIdx.x >= off) ? sh[threadIdx.x - off] : 0;
        __syncthreads();
        sh[threadIdx.x] += t;
        __syncthreads();
    }
    if (threadIdx.x < nb) g->bsum[threadIdx.x] = sh[threadIdx.x] - v;
}

__global__ __launch_bounds__(256) void scan3_2k(GP a, GP b, int nb_a, int nb_b, int N, int Etot){
    int bid = blockIdx.x; const GP* g; int lb;
    if (bid < nb_a){ g = &a; lb = bid; }
    else { lb = bid - nb_a; if (lb >= nb_b) return; g = &b; }
    int i = lb * 256 + threadIdx.x;
    if (i < N) g->rowptr[i] = g->scan1b[i] - g->counts[i] + g->bsum[lb];
    if (i == 0) g->rowptr[N] = Etot;
}

__global__ __launch_bounds__(BLK) void unzip2_k(GP a, GP b, int NB_a, int NB_b, int N){
    int bid = blockIdx.x; const GP* g; int lb;
    if (bid < NB_a){ g = &a; lb = bid; }
    else { lb = bid - NB_a; if (lb >= NB_b) return; g = &b; }
    int n = lb * BLK + threadIdx.x;
    if (n >= N) return;
    int pos = g->rowptr[n];
    int c = g->head[n];
    while (c >= 0){
        int2 p = g->pair[c];
        g->csrsrc[pos++] = p.y;
        c = p.x;
    }
}

template<int CO, bool BF16H>
__global__ __launch_bounds__(BLK) void agg2_k(GP a, GP b, const float* bias, int AB_a, int AB_b, int N){
    int bid = blockIdx.x; const GP* g; int lb;
    if (bid < AB_a){ g = &a; lb = bid; }
    else { lb = bid - AB_a; if (lb >= AB_b) return; g = &b; }
    const float* as; const float* ad; const void* h; float* outp;
    if constexpr (CO == 128){ as = g->as1; ad = g->ad1; h = g->h1b; outp = g->agg1; }
    else                    { as = g->as2; ad = g->ad2; h = g->h2b; outp = g->outp; }
    agg_dev<CO, BF16H>(lb, g->rowptr, g->csrsrc, as, ad, h, bias, outp, N);
}

// ---------------- host ----------------
extern "C" void kernel_launch(void* const* d_in, const int* in_sizes, int n_in,
                              void* d_out, int out_size, void* d_ws, size_t ws_size,
                              hipStream_t stream)
{
    const float* fea  = (const float*)d_in[0];
    const int*   ei   = (const int*)  d_in[1];
    const float* W1   = (const float*)d_in[2];
    const float* av_s1= (const float*)d_in[3];
    const float* av_d1= (const float*)d_in[4];
    const float* b1   = (const float*)d_in[5];
    const float* W2   = (const float*)d_in[6];
    const float* av_s2= (const float*)d_in[7];
    const float* av_d2= (const float*)d_in[8];
    const float* b2   = (const float*)d_in[9];
    float* out = (float*)d_out;

    const int B = 2;
    const int N = out_size / (B * 64);          // 50000
    const int E = in_sizes[1] / (2 * B);        // 800000
    const int Etot = E + N;

    // per-graph float budget (slight overestimate, h2 now bf16 but keep slack)
    size_t pg = (size_t)N*64 + (size_t)N*128 + (size_t)N*64 + 4*(size_t)N
              + 3*(size_t)N + 256 + (size_t)(N + 2) + (size_t)Etot + 2*(size_t)Etot + 8;
    size_t wtf = 8192 + 8192 + 4096 + 4096;
    bool fused = (ws_size >= (2 * pg + wtf + 64) * sizeof(float));
    int NG = fused ? 2 : 1;

    float* ws = (float*)d_ws;
    size_t off = 0;
    unsigned short* w1h = (unsigned short*)(ws + off); off += 8192;
    unsigned short* w1l = (unsigned short*)(ws + off); off += 8192;
    unsigned short* w2h = (unsigned short*)(ws + off); off += 4096;
    unsigned short* w2l = (unsigned short*)(ws + off); off += 4096;

    GP g[2];
    for (int gi = 0; gi < NG; gi++){
        GP p;
        p.h1b   = (unsigned short*)(ws + off); off += (size_t)N * 64;
        p.agg1  = ws + off; off += (size_t)N * 128;
        p.h2b   = (unsigned short*)(ws + off); off += (size_t)N * 32;
        p.as1   = ws + off; off += N;
        p.ad1   = ws + off; off += N;
        p.as2   = ws + off; off += N;
        p.ad2   = ws + off; off += N;
        p.head  = (int*)(ws + off); off += N;
        p.counts= (int*)(ws + off); off += N;
        p.scan1b= (int*)(ws + off); off += N;
        p.bsum  = (int*)(ws + off); off += 256;
        p.rowptr= (int*)(ws + off); off += (size_t)(N + 2);
        p.csrsrc= (int*)(ws + off); off += Etot;
        off += (off & 1);
        p.pair  = (int2*)(ws + off); off += 2 * (size_t)Etot;
        g[gi] = p;
    }

    const int RT  = N >> 4;                       // 3125 row-tiles
    const int GB1 = cdiv(RT, 4) * 2;              // layer-1 gemm blocks per graph (64-row x 64-col)
    const int GB2 = cdiv(RT, 4) * 2;              // layer-2 gemm blocks per graph (64-row x 32-col)
    const int LB  = cdiv(Etot, BLK);
    const int NB  = cdiv(N, BLK);
    const int nb  = cdiv(N, 256);
    const int AB  = cdiv(N, BLK / 64);

    prep2_k<<<cdiv(128*128 + 64*128, BLK), BLK, 0, stream>>>(W1, W2, w1h, w1l, w2h, w2l);

    if (fused){
        for (int bi = 0; bi < 2; bi++){
            g[bi].src = ei + (size_t)bi * 2 * E;
            g[bi].dst = g[bi].src + E;
            g[bi].X   = fea + (size_t)bi * N * 128;
            g[bi].outp= out + (size_t)bi * N * 64;
        }
        init2_k<<<cdiv(N, BLK), BLK, 0, stream>>>(g[0], g[1], 2, N);
        mega1_k<<<2*GB1 + 2*LB, 256, 0, stream>>>(g[0], g[1], w1h, w1l, av_s1, av_d1,
                                                  GB1, GB1, LB, LB, E, Etot, N);
        deg2_k  <<<2*NB, BLK, 0, stream>>>(g[0], g[1], NB, NB, N);
        scan1_2k<<<2*nb, 256, 0, stream>>>(g[0], g[1], nb, nb, N);
        scan2_2k<<<2, 256, 0, stream>>>(g[0], g[1], nb);
        scan3_2k<<<2*nb, 256, 0, stream>>>(g[0], g[1], nb, nb, N, Etot);
        unzip2_k<<<2*NB, BLK, 0, stream>>>(g[0], g[1], NB, NB, N);
        agg2_k<128,true> <<<2*AB, BLK, 0, stream>>>(g[0], g[1], b1, AB, AB, N);
        gemm2_k <<<2*GB2, 256, 0, stream>>>(g[0], g[1], w2h, w2l, av_s2, av_d2, GB2, GB2, N);
        agg2_k<64,true> <<<2*AB, BLK, 0, stream>>>(g[0], g[1], b2, AB, AB, N);
    } else {
        for (int bi = 0; bi < B; bi++){
            GP p = g[0];
            p.src = ei + (size_t)bi * 2 * E;
            p.dst = p.src + E;
            p.X   = fea + (size_t)bi * N * 128;
            p.outp= out + (size_t)bi * N * 64;
            init2_k<<<cdiv(N, BLK), BLK, 0, stream>>>(p, p, 1, N);
            mega1_k<<<GB1 + LB, 256, 0, stream>>>(p, p, w1h, w1l, av_s1, av_d1,
                                                  GB1, 0, LB, 0, E, Etot, N);
            deg2_k  <<<NB, BLK, 0, stream>>>(p, p, NB, 0, N);
            scan1_2k<<<nb, 256, 0, stream>>>(p, p, nb, 0, N);
            scan2_2k<<<1, 256, 0, stream>>>(p, p, nb);
            scan3_2k<<<nb, 256, 0, stream>>>(p, p, nb, 0, N, Etot);
            unzip2_k<<<NB, BLK, 0, stream>>>(p, p, NB, 0, N);
            agg2_k<128,true> <<<AB, BLK, 0, stream>>>(p, p, b1, AB, 0, N);
            gemm2_k <<<GB2, 256, 0, stream>>>(p, p, w2h, w2l, av_s2, av_d2, GB2, 0, N);
            agg2_k<64,true> <<<AB, BLK, 0, stream>>>(p, p, b2, AB, 0, N);
        }
    }
}

// Round 10
// 295.860 us; speedup vs baseline: 1.4409x; 1.0325x over previous
//
#include <hip/hip_runtime.h>

#define NEG_SLOPE 0.2f
static constexpr int BLK = 256;

typedef short bf16x8 __attribute__((ext_vector_type(8)));
typedef float f32x4  __attribute__((ext_vector_type(4)));
typedef unsigned short u16x8 __attribute__((ext_vector_type(8)));
typedef unsigned short u16x4 __attribute__((ext_vector_type(4)));

template<int NE> struct uvec_t;
template<> struct uvec_t<4>{ using T = u16x4; };
template<> struct uvec_t<8>{ using T = u16x8; };

static inline int cdiv(long a, long b){ return (int)((a + b - 1) / b); }

__device__ __forceinline__ unsigned short f2bf(float f){
    unsigned u = __float_as_uint(f);
    u += 0x7fff + ((u >> 16) & 1);          // RNE
    return (unsigned short)(u >> 16);
}
__device__ __forceinline__ float bf2f(unsigned short h){
    return __uint_as_float(((unsigned)h) << 16);
}

// ---------------- per-graph pointer bundle ----------------
struct GP {
    const int* src; const int* dst; const float* X;
    int* head; int2* pair; int* counts; int* scan1b; int* bsum; int* rowptr; int* csrsrc;
    unsigned short* h1b; float* agg1; unsigned short* h2b;
    float *as1, *ad1, *as2, *ad2; float* outp;
};

// ---------------- LDS-staged MFMA GEMM: h = W_split x bf16(x) ----------------
// Block = 4 row-tiles (64 rows) x one col-chunk (CT*16 cols). W hi+lo staged to LDS
// with XOR swizzle. Inner loop per ks: 2 global X loads, 8 f2bf, 2*CT ds_read_b128,
// 2*CT MFMAs (wh*xbf + wl*xbf — W exact, X rounded once).
template<int CO, int CT, bool RELU_IN, bool BF16OUT>
__device__ __forceinline__ void gemm_dev(
    int bid, const float* __restrict__ X,
    const unsigned short* __restrict__ Wt_hi, const unsigned short* __restrict__ Wt_lo,
    const float* __restrict__ avs, const float* __restrict__ avd,
    void* __restrict__ Hout, float* __restrict__ as_out, float* __restrict__ ad_out,
    int N, unsigned short* smem)
{
    constexpr int CHUNKS = CO / (CT * 16);
    constexpr int HWB = CT * 4096;           // bytes of hi matrix in LDS
    int ch, rtb;
    if (CHUNKS == 1){ ch = 0; rtb = bid; } else { ch = bid & 1; rtb = bid >> 1; }
    int c0 = ch * (CT * 16);

    {
        const char* srch = (const char*)(Wt_hi + (size_t)c0 * 128);
        const char* srcl = (const char*)(Wt_lo + (size_t)c0 * 128);
        #pragma unroll
        for (int it = 0; it < CT * 2; ++it){
            int o = (it * 256 + (int)threadIdx.x) * 16;
            const char* sp = (o < HWB) ? (srch + o) : (srcl + (o - HWB));
            u16x8 v = *(const u16x8*)sp;
            int so = o ^ (((o >> 8) & 7) << 4);
            *(u16x8*)((char*)smem + so) = v;
        }
    }
    __syncthreads();

    int wave = threadIdx.x >> 6;
    int lane = threadIdx.x & 63;
    int rt = rtb * 4 + wave;
    if (rt >= (N >> 4)) return;
    int r0 = rt << 4;
    int rl = lane & 15, g = lane >> 4;
    const float* xrow = X + (long)(r0 + rl) * 128 + g * 8;

    f32x4 acc[CT];
    #pragma unroll
    for (int t = 0; t < CT; t++) acc[t] = (f32x4)(0.f);

    int sw = (rl & 7) << 4;
    #pragma unroll
    for (int ks = 0; ks < 4; ks++){
        float4 xa = *(const float4*)(xrow + ks * 32);
        float4 xb = *(const float4*)(xrow + ks * 32 + 4);
        float xv[8] = {xa.x, xa.y, xa.z, xa.w, xb.x, xb.y, xb.z, xb.w};
        bf16x8 xbf;
        #pragma unroll
        for (int j = 0; j < 8; j++){
            float x = xv[j];
            if (RELU_IN) x = fmaxf(x, 0.f);
            xbf[j] = (short)f2bf(x);
        }
        int rbase = rl * 256 + ks * 64 + g * 16;
        #pragma unroll
        for (int t = 0; t < CT; t++){
            bf16x8 wh = *(const bf16x8*)((char*)smem + ((t * 4096 + rbase) ^ sw));
            bf16x8 wl = *(const bf16x8*)((char*)smem + ((HWB + t * 4096 + rbase) ^ sw));
            acc[t] = __builtin_amdgcn_mfma_f32_16x16x32_bf16(wh, xbf, acc[t], 0, 0, 0);
            acc[t] = __builtin_amdgcn_mfma_f32_16x16x32_bf16(wl, xbf, acc[t], 0, 0, 0);
        }
    }

    float ps = 0.f, pd = 0.f;
    #pragma unroll
    for (int t = 0; t < CT; t++){
        int c = c0 + t * 16 + 4 * g;
        float4 vs4 = *(const float4*)(avs + c);
        float4 vd4 = *(const float4*)(avd + c);
        ps += acc[t][0]*vs4.x + acc[t][1]*vs4.y + acc[t][2]*vs4.z + acc[t][3]*vs4.w;
        pd += acc[t][0]*vd4.x + acc[t][1]*vd4.y + acc[t][2]*vd4.z + acc[t][3]*vd4.w;
        long base = (long)(r0 + rl) * CO + c;
        if (BF16OUT){
            u16x4 pk;
            #pragma unroll
            for (int r = 0; r < 4; r++) pk[r] = f2bf(acc[t][r]);
            *(u16x4*)((unsigned short*)Hout + base) = pk;
        } else {
            float4 pv;
            pv.x = acc[t][0]; pv.y = acc[t][1]; pv.z = acc[t][2]; pv.w = acc[t][3];
            *(float4*)((float*)Hout + base) = pv;
        }
    }
    ps += __shfl_xor(ps, 16, 64); ps += __shfl_xor(ps, 32, 64);
    pd += __shfl_xor(pd, 16, 64); pd += __shfl_xor(pd, 32, 64);
    if (g == 0){
        unsafeAtomicAdd(as_out + r0 + rl, ps);
        unsafeAtomicAdd(ad_out + r0 + rl, pd);
    }
}

__device__ __forceinline__ void link_dev(
    int bid, const int* __restrict__ src, const int* __restrict__ dst,
    int E, int Etot, int* __restrict__ head, int2* __restrict__ pair)
{
    int e = bid * BLK + threadIdx.x;
    if (e >= Etot) return;
    int s, d;
    if (e < E){ s = src[e]; d = dst[e]; } else { s = e - E; d = s; }
    int old = atomicExch(head + d, e);
    pair[e] = make_int2(old, s);
}

// fused softmax + aggregation, one wave per dst node (quarter-wave gather)
template<int CO, bool BF16H>
__device__ __forceinline__ void agg_dev(
    int bid, const int* __restrict__ rowptr, const int* __restrict__ csr_src,
    const float* __restrict__ as, const float* __restrict__ ad,
    const void* __restrict__ h, const float* __restrict__ bias,
    float* __restrict__ out, int N)
{
    constexpr int ELEMS = CO / 16;
    using uvec = typename uvec_t<ELEMS>::T;
    int node = bid * (BLK / 64) + (threadIdx.x >> 6);
    int lane = threadIdx.x & 63;
    if (node >= N) return;
    int start = rowptr[node];
    int deg   = rowptr[node + 1] - start;
    float adv = ad[node];
    int g  = lane >> 4;
    int ql = lane & 15;

    const unsigned short* hb = (const unsigned short*)h;
    const float*          hf = (const float*)h;

    if (deg <= 64){
        int   s = 0;
        float e = -1e30f;
        if (lane < deg){
            s = csr_src[start + lane];
            float v = as[s] + adv;
            e = v > 0.f ? v : NEG_SLOPE * v;
        }
        float m = e;
        #pragma unroll
        for (int off = 32; off; off >>= 1) m = fmaxf(m, __shfl_xor(m, off, 64));
        float ex = (lane < deg) ? __expf(e - m) : 0.f;
        float sum = ex;
        #pragma unroll
        for (int off = 32; off; off >>= 1) sum += __shfl_xor(sum, off, 64);
        float alpha = ex / (sum + 1e-16f);

        float acc[ELEMS];
        #pragma unroll
        for (int i = 0; i < ELEMS; i++) acc[i] = 0.f;

        int j = 0;
        for (; j + 7 < deg; j += 8){
            int e0 = j + g, e1 = j + 4 + g;
            int   s0 = __shfl(s, e0, 64),      s1 = __shfl(s, e1, 64);
            float a0 = __shfl(alpha, e0, 64),  a1 = __shfl(alpha, e1, 64);
            if (BF16H){
                uvec h0 = *(const uvec*)(hb + (long)s0 * CO + ql * ELEMS);
                uvec h1 = *(const uvec*)(hb + (long)s1 * CO + ql * ELEMS);
                #pragma unroll
                for (int i = 0; i < ELEMS; i++)
                    acc[i] += a0 * bf2f(h0[i]) + a1 * bf2f(h1[i]);
            } else {
                float4 h0 = *(const float4*)(hf + (long)s0 * CO + ql * ELEMS);
                float4 h1 = *(const float4*)(hf + (long)s1 * CO + ql * ELEMS);
                acc[0]       += a0 * h0.x + a1 * h1.x;
                acc[1]       += a0 * h0.y + a1 * h1.y;
                acc[2]       += a0 * h0.z + a1 * h1.z;
                acc[ELEMS-1] += a0 * h0.w + a1 * h1.w;
            }
        }
        for (; j + 3 < deg; j += 4){
            int e0 = j + g;
            int   s0 = __shfl(s, e0, 64);
            float a0 = __shfl(alpha, e0, 64);
            if (BF16H){
                uvec h0 = *(const uvec*)(hb + (long)s0 * CO + ql * ELEMS);
                #pragma unroll
                for (int i = 0; i < ELEMS; i++) acc[i] += a0 * bf2f(h0[i]);
            } else {
                float4 h0 = *(const float4*)(hf + (long)s0 * CO + ql * ELEMS);
                acc[0] += a0 * h0.x; acc[1] += a0 * h0.y;
                acc[2] += a0 * h0.z; acc[ELEMS-1] += a0 * h0.w;
            }
        }
        if (j < deg){
            int rem = deg - j;
            int e0 = min(j + g, deg - 1);
            int   s0 = __shfl(s, e0, 64);
            float a0 = __shfl(alpha, e0, 64);
            if (g < rem){
                if (BF16H){
                    uvec h0 = *(const uvec*)(hb + (long)s0 * CO + ql * ELEMS);
                    #pragma unroll
                    for (int i = 0; i < ELEMS; i++) acc[i] += a0 * bf2f(h0[i]);
                } else {
                    float4 h0 = *(const float4*)(hf + (long)s0 * CO + ql * ELEMS);
                    acc[0] += a0 * h0.x; acc[1] += a0 * h0.y;
                    acc[2] += a0 * h0.z; acc[ELEMS-1] += a0 * h0.w;
                }
            }
        }
        #pragma unroll
        for (int i = 0; i < ELEMS; i++){
            acc[i] += __shfl_xor(acc[i], 16, 64);
            acc[i] += __shfl_xor(acc[i], 32, 64);
        }
        if (g == 0){
            float* o = out + (long)node * CO + ql * ELEMS;
            #pragma unroll
            for (int i = 0; i < ELEMS; i += 4){
                float4 ov;
                ov.x = acc[i+0] + bias[ql * ELEMS + i + 0];
                ov.y = acc[i+1] + bias[ql * ELEMS + i + 1];
                ov.z = acc[i+2] + bias[ql * ELEMS + i + 2];
                ov.w = acc[i+3] + bias[ql * ELEMS + i + 3];
                *(float4*)(o + i) = ov;
            }
        }
    } else {
        constexpr int VPL = CO / 64;
        float accf[VPL];
        #pragma unroll
        for (int i = 0; i < VPL; i++) accf[i] = 0.f;
        float m = -1e30f;
        for (int jj = lane; jj < deg; jj += 64){
            int sj = csr_src[start + jj];
            float v = as[sj] + adv; v = v > 0.f ? v : NEG_SLOPE * v;
            m = fmaxf(m, v);
        }
        #pragma unroll
        for (int off = 32; off; off >>= 1) m = fmaxf(m, __shfl_xor(m, off, 64));
        float sum = 0.f;
        for (int jj = lane; jj < deg; jj += 64){
            int sj = csr_src[start + jj];
            float v = as[sj] + adv; v = v > 0.f ? v : NEG_SLOPE * v;
            sum += __expf(v - m);
        }
        #pragma unroll
        for (int off = 32; off; off >>= 1) sum += __shfl_xor(sum, off, 64);
        float inv = 1.f / (sum + 1e-16f);
        for (int jj = 0; jj < deg; jj++){
            int sj = csr_src[start + jj];
            float v = as[sj] + adv; v = v > 0.f ? v : NEG_SLOPE * v;
            float aj = __expf(v - m) * inv;
            if (BF16H){
                const unsigned short* hr = hb + (long)sj * CO + lane * VPL;
                #pragma unroll
                for (int i = 0; i < VPL; i++) accf[i] += aj * bf2f(hr[i]);
            } else {
                const float* hr = hf + (long)sj * CO + lane * VPL;
                #pragma unroll
                for (int i = 0; i < VPL; i++) accf[i] += aj * hr[i];
            }
        }
        float* o = out + (long)node * CO + lane * VPL;
        #pragma unroll
        for (int i = 0; i < VPL; i++) o[i] = accf[i] + bias[lane * VPL + i];
    }
}

// ---------------- fused kernels ----------------
// setup: W prep (transpose+split) AND per-graph init (head/-1, as/ad zero) in one launch
__global__ __launch_bounds__(BLK) void setup_k(
    GP a, GP b, int ng, int N,
    const float* __restrict__ W1, const float* __restrict__ W2,
    unsigned short* __restrict__ w1h, unsigned short* __restrict__ w1l,
    unsigned short* __restrict__ w2h, unsigned short* __restrict__ w2l)
{
    int i = blockIdx.x * BLK + threadIdx.x;
    if (i < N){
        a.head[i] = -1;
        a.as1[i] = 0.f; a.ad1[i] = 0.f; a.as2[i] = 0.f; a.ad2[i] = 0.f;
        if (ng > 1){
            b.head[i] = -1;
            b.as1[i] = 0.f; b.ad1[i] = 0.f; b.as2[i] = 0.f; b.ad2[i] = 0.f;
        }
    }
    if (i < 128 * 128){
        int c = i >> 7, k = i & 127;
        float w = W1[k * 128 + c];
        unsigned short hi = f2bf(w);
        w1h[i] = hi; w1l[i] = f2bf(w - bf2f(hi));
        if (i < 64 * 128){
            int c2 = i >> 7, k2 = i & 127;
            float w2 = W2[k2 * 64 + c2];
            unsigned short hi2 = f2bf(w2);
            w2h[i] = hi2; w2l[i] = f2bf(w2 - bf2f(hi2));
        }
    }
}

// mega1: layer-1 GEMMs (both graphs) + link (both graphs), Bresenham-interleaved
__global__ __launch_bounds__(256, 4) void mega1_k(
    GP a, GP b, const unsigned short* w1h, const unsigned short* w1l,
    const float* avs1, const float* avd1,
    int GB_a, int GB_b, int LB_a, int LB_b, int E, int Etot, int N)
{
    __shared__ unsigned short smem[16384];   // 32KB: W1 chunk hi+lo
    int GT = GB_a + GB_b;
    int total = GT + LB_a + LB_b;
    int bid = blockIdx.x;
    long lo  = (long)bid * GT / total;
    long hi2 = (long)(bid + 1) * GT / total;
    if (hi2 > lo){
        int gi = (int)lo;
        if (gi < GB_a) gemm_dev<128,4,false,true>(gi, a.X, w1h, w1l, avs1, avd1, a.h1b, a.as1, a.ad1, N, smem);
        else           gemm_dev<128,4,false,true>(gi - GB_a, b.X, w1h, w1l, avs1, avd1, b.h1b, b.as1, b.ad1, N, smem);
    } else {
        int l = bid - (int)lo;
        if (l < LB_a) link_dev(l, a.src, a.dst, E, Etot, a.head, a.pair);
        else { l -= LB_a; if (l < LB_b) link_dev(l, b.src, b.dst, E, Etot, b.head, b.pair); }
    }
}

__global__ __launch_bounds__(256, 4) void gemm2_k(
    GP a, GP b, const unsigned short* w2h, const unsigned short* w2l,
    const float* avs2, const float* avd2, int GB_a, int GB_b, int N)
{
    __shared__ unsigned short smem[8192];    // 16KB: W2 chunk hi+lo
    int bid = blockIdx.x;
    if (bid < GB_a) gemm_dev<64,2,true,true>(bid, a.agg1, w2h, w2l, avs2, avd2, a.h2b, a.as2, a.ad2, N, smem);
    else { bid -= GB_a; if (bid < GB_b) gemm_dev<64,2,true,true>(bid, b.agg1, w2h, w2l, avs2, avd2, b.h2b, b.as2, b.ad2, N, smem); }
}

// degscan: chain-walk degrees + in-block inclusive scan (fuses deg_k + scan1_k)
__global__ __launch_bounds__(256) void degscan_k(GP a, GP b, int nb_a, int nb_b, int N){
    int bid = blockIdx.x; const GP* g; int lb;
    if (bid < nb_a){ g = &a; lb = bid; }
    else { lb = bid - nb_a; if (lb >= nb_b) return; g = &b; }
    __shared__ int sh[256];
    int i = lb * 256 + threadIdx.x;
    int len = 0;
    if (i < N){
        int c = g->head[i];
        while (c >= 0){ len++; c = g->pair[c].x; }
        g->counts[i] = len;
    }
    sh[threadIdx.x] = len;
    __syncthreads();
    #pragma unroll
    for (int off = 1; off < 256; off <<= 1){
        int t = (threadIdx.x >= off) ? sh[threadIdx.x - off] : 0;
        __syncthreads();
        sh[threadIdx.x] += t;
        __syncthreads();
    }
    if (i < N) g->scan1b[i] = sh[threadIdx.x];
    if (threadIdx.x == 255) g->bsum[lb] = sh[255];
}

__global__ __launch_bounds__(256) void scan2_2k(GP a, GP b, int nb){
    const GP* g = (blockIdx.x == 0) ? &a : &b;
    __shared__ int sh[256];
    int v = (threadIdx.x < nb) ? g->bsum[threadIdx.x] : 0;
    sh[threadIdx.x] = v;
    __syncthreads();
    #pragma unroll
    for (int off = 1; off < 256; off <<= 1){
        int t = (threadIdx.x >= off) ? sh[threadIdx.x - off] : 0;
        __syncthreads();
        sh[threadIdx.x] += t;
        __syncthreads();
    }
    if (threadIdx.x < nb) g->bsum[threadIdx.x] = sh[threadIdx.x] - v;
}

// ptrunzip: rowptr computation + chain unzip into CSR (fuses scan3_k + unzip_k)
__global__ __launch_bounds__(256) void ptrunzip_k(GP a, GP b, int nb_a, int nb_b, int N, int Etot){
    int bid = blockIdx.x; const GP* g; int lb;
    if (bid < nb_a){ g = &a; lb = bid; }
    else { lb = bid - nb_a; if (lb >= nb_b) return; g = &b; }
    int i = lb * 256 + threadIdx.x;
    if (i >= N) return;
    int pos = g->scan1b[i] - g->counts[i] + g->bsum[lb];
    g->rowptr[i] = pos;
    if (i == 0) g->rowptr[N] = Etot;
    int c = g->head[i];
    while (c >= 0){
        int2 p = g->pair[c];
        g->csrsrc[pos++] = p.y;
        c = p.x;
    }
}

template<int CO, bool BF16H>
__global__ __launch_bounds__(BLK) void agg2_k(GP a, GP b, const float* bias, int AB_a, int AB_b, int N){
    int bid = blockIdx.x; const GP* g; int lb;
    if (bid < AB_a){ g = &a; lb = bid; }
    else { lb = bid - AB_a; if (lb >= AB_b) return; g = &b; }
    const float* as; const float* ad; const void* h; float* outp;
    if constexpr (CO == 128){ as = g->as1; ad = g->ad1; h = g->h1b; outp = g->agg1; }
    else                    { as = g->as2; ad = g->ad2; h = g->h2b; outp = g->outp; }
    agg_dev<CO, BF16H>(lb, g->rowptr, g->csrsrc, as, ad, h, bias, outp, N);
}

// ---------------- host ----------------
extern "C" void kernel_launch(void* const* d_in, const int* in_sizes, int n_in,
                              void* d_out, int out_size, void* d_ws, size_t ws_size,
                              hipStream_t stream)
{
    const float* fea  = (const float*)d_in[0];
    const int*   ei   = (const int*)  d_in[1];
    const float* W1   = (const float*)d_in[2];
    const float* av_s1= (const float*)d_in[3];
    const float* av_d1= (const float*)d_in[4];
    const float* b1   = (const float*)d_in[5];
    const float* W2   = (const float*)d_in[6];
    const float* av_s2= (const float*)d_in[7];
    const float* av_d2= (const float*)d_in[8];
    const float* b2   = (const float*)d_in[9];
    float* out = (float*)d_out;

    const int B = 2;
    const int N = out_size / (B * 64);          // 50000
    const int E = in_sizes[1] / (2 * B);        // 800000
    const int Etot = E + N;

    size_t pg = (size_t)N*64 + (size_t)N*128 + (size_t)N*64 + 4*(size_t)N
              + 3*(size_t)N + 256 + (size_t)(N + 2) + (size_t)Etot + 2*(size_t)Etot + 8;
    size_t wtf = 8192 + 8192 + 4096 + 4096;
    bool fused = (ws_size >= (2 * pg + wtf + 64) * sizeof(float));
    int NG = fused ? 2 : 1;

    float* ws = (float*)d_ws;
    size_t off = 0;
    unsigned short* w1h = (unsigned short*)(ws + off); off += 8192;
    unsigned short* w1l = (unsigned short*)(ws + off); off += 8192;
    unsigned short* w2h = (unsigned short*)(ws + off); off += 4096;
    unsigned short* w2l = (unsigned short*)(ws + off); off += 4096;

    GP g[2];
    for (int gi = 0; gi < NG; gi++){
        GP p;
        p.h1b   = (unsigned short*)(ws + off); off += (size_t)N * 64;
        p.agg1  = ws + off; off += (size_t)N * 128;
        p.h2b   = (unsigned short*)(ws + off); off += (size_t)N * 32;
        p.as1   = ws + off; off += N;
        p.ad1   = ws + off; off += N;
        p.as2   = ws + off; off += N;
        p.ad2   = ws + off; off += N;
        p.head  = (int*)(ws + off); off += N;
        p.counts= (int*)(ws + off); off += N;
        p.scan1b= (int*)(ws + off); off += N;
        p.bsum  = (int*)(ws + off); off += 256;
        p.rowptr= (int*)(ws + off); off += (size_t)(N + 2);
        p.csrsrc= (int*)(ws + off); off += Etot;
        off += (off & 1);
        p.pair  = (int2*)(ws + off); off += 2 * (size_t)Etot;
        g[gi] = p;
    }

    const int RT  = N >> 4;
    const int GB1 = cdiv(RT, 4) * 2;
    const int GB2 = cdiv(RT, 4) * 2;
    const int LB  = cdiv(Etot, BLK);
    const int nb  = cdiv(N, 256);
    const int AB  = cdiv(N, BLK / 64);

    if (fused){
        for (int bi = 0; bi < 2; bi++){
            g[bi].src = ei + (size_t)bi * 2 * E;
            g[bi].dst = g[bi].src + E;
            g[bi].X   = fea + (size_t)bi * N * 128;
            g[bi].outp= out + (size_t)bi * N * 64;
        }
        setup_k<<<cdiv(N, BLK), BLK, 0, stream>>>(g[0], g[1], 2, N, W1, W2, w1h, w1l, w2h, w2l);
        mega1_k<<<2*GB1 + 2*LB, 256, 0, stream>>>(g[0], g[1], w1h, w1l, av_s1, av_d1,
                                                  GB1, GB1, LB, LB, E, Etot, N);
        degscan_k<<<2*nb, 256, 0, stream>>>(g[0], g[1], nb, nb, N);
        scan2_2k<<<2, 256, 0, stream>>>(g[0], g[1], nb);
        ptrunzip_k<<<2*nb, 256, 0, stream>>>(g[0], g[1], nb, nb, N, Etot);
        agg2_k<128,true> <<<2*AB, BLK, 0, stream>>>(g[0], g[1], b1, AB, AB, N);
        gemm2_k <<<2*GB2, 256, 0, stream>>>(g[0], g[1], w2h, w2l, av_s2, av_d2, GB2, GB2, N);
        agg2_k<64,true> <<<2*AB, BLK, 0, stream>>>(g[0], g[1], b2, AB, AB, N);
    } else {
        for (int bi = 0; bi < B; bi++){
            GP p = g[0];
            p.src = ei + (size_t)bi * 2 * E;
            p.dst = p.src + E;
            p.X   = fea + (size_t)bi * N * 128;
            p.outp= out + (size_t)bi * N * 64;
            setup_k<<<cdiv(N, BLK), BLK, 0, stream>>>(p, p, 1, N, W1, W2, w1h, w1l, w2h, w2l);
            mega1_k<<<GB1 + LB, 256, 0, stream>>>(p, p, w1h, w1l, av_s1, av_d1,
                                                  GB1, 0, LB, 0, E, Etot, N);
            degscan_k<<<nb, 256, 0, stream>>>(p, p, nb, 0, N);
            scan2_2k<<<1, 256, 0, stream>>>(p, p, nb);
            ptrunzip_k<<<nb, 256, 0, stream>>>(p, p, nb, 0, N, Etot);
            agg2_k<128,true> <<<AB, BLK, 0, stream>>>(p, p, b1, AB, 0, N);
            gemm2_k <<<GB2, 256, 0, stream>>>(p, p, w2h, w2l, av_s2, av_d2, GB2, 0, N);
            agg2_k<64,true> <<<AB, BLK, 0, stream>>>(p, p, b2, AB, 0, N);
        }
    }
}